// Round 1
// baseline (1344.730 us; speedup 1.0000x reference)
//
#include <hip/hip_runtime.h>
#include <math.h>

#define N_NODES 50000
#define N_EDGES 800000
#define F_INPUT 128
#define HEADS 4
#define DHID 64
#define HID 256   // HEADS*DHID

// ---------------- CSR build ----------------

__global__ void hist_kernel(const int* __restrict__ dst, int* __restrict__ counts) {
    int e = blockIdx.x * 256 + threadIdx.x;
    if (e < N_EDGES) atomicAdd(&counts[dst[e]], 1);
}

// single-block exclusive scan over counts -> row_ptr[0..N]
__global__ void scan_kernel(const int* __restrict__ counts, int* __restrict__ row_ptr) {
    __shared__ int buf[1024];
    __shared__ int carry;
    if (threadIdx.x == 0) carry = 0;
    __syncthreads();
    for (int base = 0; base < N_NODES; base += 1024) {
        int i = base + (int)threadIdx.x;
        int v = (i < N_NODES) ? counts[i] : 0;
        buf[threadIdx.x] = v;
        __syncthreads();
        for (int off = 1; off < 1024; off <<= 1) {
            int t = (threadIdx.x >= (unsigned)off) ? buf[threadIdx.x - off] : 0;
            __syncthreads();
            buf[threadIdx.x] += t;
            __syncthreads();
        }
        int incl = buf[threadIdx.x];
        int c = carry;
        if (i < N_NODES) row_ptr[i + 1] = c + incl;
        __syncthreads();
        if (threadIdx.x == 1023) carry = c + incl;
        __syncthreads();
    }
    if (threadIdx.x == 0) row_ptr[0] = 0;
}

__global__ void scatter_kernel(const int* __restrict__ src, const int* __restrict__ dst,
                               const int* __restrict__ row_ptr, int* __restrict__ cursor,
                               int* __restrict__ esrc) {
    int e = blockIdx.x * 256 + threadIdx.x;
    if (e < N_EDGES) {
        int d = dst[e];
        int pos = row_ptr[d] + atomicAdd(&cursor[d], 1);
        esrc[pos] = src[e];
    }
}

// ---------------- GEMM: C[N x 256] = A[N x K] * W[K x 256], fp32 ----------------
// block 256 threads, tile 32 rows x 256 cols, register tile 4x8 per thread.

__global__ __launch_bounds__(256) void gemm_kernel(const float* __restrict__ A,
                                                   const float* __restrict__ W,
                                                   float* __restrict__ C, int K) {
    __shared__ __align__(16) float As[32][40];    // [kk][row], padded stride 40 (16B-aligned rows)
    __shared__ __align__(16) float Ws[32][256];   // [kk][col]
    int tid = threadIdx.x;
    int tx = tid & 31;        // col group: cols tx*8 .. tx*8+7
    int ty = tid >> 5;        // row group: rows ty*4 .. ty*4+3
    int row0 = blockIdx.x * 32;

    float acc[4][8];
#pragma unroll
    for (int i = 0; i < 4; i++)
#pragma unroll
        for (int j = 0; j < 8; j++) acc[i][j] = 0.f;

    for (int k0 = 0; k0 < K; k0 += 32) {
        // load A chunk (32 rows x 32 k), transposed into As[kk][row]
        int r = tid >> 3;
        int kk0 = (tid & 7) * 4;
        float4 av = make_float4(0.f, 0.f, 0.f, 0.f);
        int grow = row0 + r;
        if (grow < N_NODES) av = *(const float4*)&A[(size_t)grow * K + k0 + kk0];
        As[kk0 + 0][r] = av.x;
        As[kk0 + 1][r] = av.y;
        As[kk0 + 2][r] = av.z;
        As[kk0 + 3][r] = av.w;
        // load W chunk (32 k x 256 cols)
#pragma unroll
        for (int j = 0; j < 8; j++) {
            int idx4 = tid + j * 256;
            int kk = idx4 >> 6;
            int c4 = idx4 & 63;
            *(float4*)&Ws[kk][c4 * 4] = *(const float4*)&W[(size_t)(k0 + kk) * HID + c4 * 4];
        }
        __syncthreads();
#pragma unroll
        for (int kk = 0; kk < 32; ++kk) {
            float4 a4 = *(const float4*)&As[kk][ty * 4];
            float4 w0 = *(const float4*)&Ws[kk][tx * 8];
            float4 w1 = *(const float4*)&Ws[kk][tx * 8 + 4];
            float aa[4] = {a4.x, a4.y, a4.z, a4.w};
            float ww[8] = {w0.x, w0.y, w0.z, w0.w, w1.x, w1.y, w1.z, w1.w};
#pragma unroll
            for (int i = 0; i < 4; i++)
#pragma unroll
                for (int j = 0; j < 8; j++) acc[i][j] += aa[i] * ww[j];
        }
        __syncthreads();
    }
#pragma unroll
    for (int i = 0; i < 4; i++) {
        int grow = row0 + ty * 4 + i;
        if (grow < N_NODES) {
            float4 o0 = make_float4(acc[i][0], acc[i][1], acc[i][2], acc[i][3]);
            float4 o1 = make_float4(acc[i][4], acc[i][5], acc[i][6], acc[i][7]);
            *(float4*)&C[(size_t)grow * HID + tx * 8] = o0;
            *(float4*)&C[(size_t)grow * HID + tx * 8 + 4] = o1;
        }
    }
}

// ---------------- el/er: per (node, head) dot(feat, al/ar) ----------------
// one block per node, wave w = head h, lane = dim d.
__global__ __launch_bounds__(256) void elr_kernel(const float* __restrict__ feat,
                                                  const float* __restrict__ al,
                                                  const float* __restrict__ ar,
                                                  float* __restrict__ el, float* __restrict__ er) {
    int n = blockIdx.x;
    int h = threadIdx.x >> 6;
    int lane = threadIdx.x & 63;
    float v = feat[(size_t)n * HID + h * DHID + lane];
    float pl = v * al[h * DHID + lane];
    float pr = v * ar[h * DHID + lane];
#pragma unroll
    for (int off = 32; off; off >>= 1) {
        pl += __shfl_down(pl, off, 64);
        pr += __shfl_down(pr, off, 64);
    }
    if (lane == 0) {
        el[n * HEADS + h] = pl;
        er[n * HEADS + h] = pr;
    }
}

// ---------------- per-dst softmax + aggregation + epilogue ----------------
// one block per dst node; wave = head; lane = feature dim.
__global__ __launch_bounds__(256) void agg_kernel(const float* __restrict__ feat,
                                                  const float* __restrict__ el,
                                                  const float* __restrict__ er,
                                                  const int* __restrict__ row_ptr,
                                                  const int* __restrict__ esrc,
                                                  const float* __restrict__ res,
                                                  const float* __restrict__ bias,
                                                  float* __restrict__ out,
                                                  int do_relu, int do_mean) {
    int n = blockIdx.x;
    int h = threadIdx.x >> 6;
    int lane = threadIdx.x & 63;
    int start = row_ptr[n];
    int deg = row_ptr[n + 1] - start;
    float ern = er[n * HEADS + h];

    // pass 1: max logit
    float m = -1e30f;
    for (int base = 0; base < deg; base += 64) {
        int e = base + lane;
        if (e < deg) {
            int s = esrc[start + e];
            float x = el[s * HEADS + h] + ern;
            x = x > 0.f ? x : 0.2f * x;
            m = fmaxf(m, x);
        }
    }
#pragma unroll
    for (int off = 32; off; off >>= 1) m = fmaxf(m, __shfl_xor(m, off, 64));

    // pass 2: denom
    float sum = 0.f;
    for (int base = 0; base < deg; base += 64) {
        int e = base + lane;
        if (e < deg) {
            int s = esrc[start + e];
            float x = el[s * HEADS + h] + ern;
            x = x > 0.f ? x : 0.2f * x;
            sum += __expf(x - m);
        }
    }
#pragma unroll
    for (int off = 32; off; off >>= 1) sum += __shfl_xor(sum, off, 64);
    float inv_denom = 1.f / fmaxf(sum, 1e-16f);

    // pass 3: aggregate alpha * feat[src]
    float acc = 0.f;
    for (int base = 0; base < deg; base += 64) {
        int e = base + lane;
        float alpha = 0.f;
        int s = 0;
        if (e < deg) {
            s = esrc[start + e];
            float x = el[s * HEADS + h] + ern;
            x = x > 0.f ? x : 0.2f * x;
            alpha = __expf(x - m) * inv_denom;
        }
        int cnt = min(64, deg - base);
        for (int j = 0; j < cnt; j++) {
            float a = __shfl(alpha, j, 64);
            int ss = __shfl(s, j, 64);
            acc += a * feat[(size_t)ss * HID + h * DHID + lane];
        }
    }

    float o = acc + res[(size_t)n * HID + h * DHID + lane] + bias[h * DHID + lane];
    if (do_relu) o = fmaxf(o, 0.f);
    if (!do_mean) {
        out[(size_t)n * HID + h * DHID + lane] = o;
    } else {
        __shared__ float hb[HEADS][DHID];
        hb[h][lane] = o;
        __syncthreads();
        if (h == 0) {
            float mo = 0.25f * (hb[0][lane] + hb[1][lane] + hb[2][lane] + hb[3][lane]);
            out[(size_t)n * DHID + lane] = mo;
        }
    }
}

// ---------------- launch ----------------

extern "C" void kernel_launch(void* const* d_in, const int* in_sizes, int n_in,
                              void* d_out, int out_size, void* d_ws, size_t ws_size,
                              hipStream_t stream) {
    const float* x     = (const float*)d_in[0];
    const int*   ei    = (const int*)d_in[1];
    const float* W0    = (const float*)d_in[2];
    const float* W1    = (const float*)d_in[3];
    const float* W2    = (const float*)d_in[4];
    const float* al0   = (const float*)d_in[5];
    const float* al1   = (const float*)d_in[6];
    const float* al2   = (const float*)d_in[7];
    const float* ar0   = (const float*)d_in[8];
    const float* ar1   = (const float*)d_in[9];
    const float* ar2   = (const float*)d_in[10];
    const float* b0    = (const float*)d_in[11];
    const float* b1    = (const float*)d_in[12];
    const float* b2    = (const float*)d_in[13];
    const float* resW0 = (const float*)d_in[14];
    float* out = (float*)d_out;

    const int* srcp = ei;
    const int* dstp = ei + N_EDGES;

    char* p = (char*)d_ws;
    auto alloc = [&](size_t bytes) -> char* {
        char* r = p;
        p += (bytes + 255) & ~(size_t)255;
        return r;
    };
    float* bufA   = (float*)alloc((size_t)N_NODES * HID * 4);
    float* bufB   = (float*)alloc((size_t)N_NODES * HID * 4);   // feat
    float* bufC   = (float*)alloc((size_t)N_NODES * HID * 4);
    float* el     = (float*)alloc((size_t)N_NODES * HEADS * 4);
    float* er     = (float*)alloc((size_t)N_NODES * HEADS * 4);
    int*   counts = (int*)alloc((size_t)N_NODES * 4);
    int*   rowptr = (int*)alloc((size_t)(N_NODES + 1) * 4);
    int*   esrc   = (int*)alloc((size_t)N_EDGES * 4);

    const int EB = (N_EDGES + 255) / 256;
    const int GB = (N_NODES + 31) / 32;

    // CSR by dst (rebuilt every call; ws is re-poisoned between calls)
    hipMemsetAsync(counts, 0, (size_t)N_NODES * 4, stream);
    hist_kernel<<<EB, 256, 0, stream>>>(dstp, counts);
    scan_kernel<<<1, 1024, 0, stream>>>(counts, rowptr);
    hipMemsetAsync(counts, 0, (size_t)N_NODES * 4, stream);
    scatter_kernel<<<EB, 256, 0, stream>>>(srcp, dstp, rowptr, counts, esrc);

    // layer 0: feat = x@W0 -> B ; res0 = x@resW0 -> C ; out -> A (relu)
    gemm_kernel<<<GB, 256, 0, stream>>>(x, W0, bufB, F_INPUT);
    gemm_kernel<<<GB, 256, 0, stream>>>(x, resW0, bufC, F_INPUT);
    elr_kernel<<<N_NODES, 256, 0, stream>>>(bufB, al0, ar0, el, er);
    agg_kernel<<<N_NODES, 256, 0, stream>>>(bufB, el, er, rowptr, esrc, bufC, b0, bufA, 1, 0);

    // layer 1: feat = A@W1 -> B ; res = A ; out -> C (relu)
    gemm_kernel<<<GB, 256, 0, stream>>>(bufA, W1, bufB, HID);
    elr_kernel<<<N_NODES, 256, 0, stream>>>(bufB, al1, ar1, el, er);
    agg_kernel<<<N_NODES, 256, 0, stream>>>(bufB, el, er, rowptr, esrc, bufA, b1, bufC, 1, 0);

    // layer 2: feat = C@W2 -> B ; res = C ; out -> d_out (mean over heads, no relu)
    gemm_kernel<<<GB, 256, 0, stream>>>(bufC, W2, bufB, HID);
    elr_kernel<<<N_NODES, 256, 0, stream>>>(bufB, al2, ar2, el, er);
    agg_kernel<<<N_NODES, 256, 0, stream>>>(bufB, el, er, rowptr, esrc, bufC, b2, out, 0, 1);
}

// Round 2
// 608.486 us; speedup vs baseline: 2.2100x; 2.2100x over previous
//
#include <hip/hip_runtime.h>
#include <math.h>

#define N_NODES 50000
#define N_EDGES 800000
#define F_INPUT 128
#define HEADS 4
#define DHID 64
#define HID 256          // HEADS*DHID
#define M_PAD 50048      // 782 * 64 (GEMM row-tile padding)

typedef _Float16 half8 __attribute__((ext_vector_type(8)));
typedef _Float16 half4 __attribute__((ext_vector_type(4)));
typedef float f32x4 __attribute__((ext_vector_type(4)));

// ---------------- CSR build ----------------

__global__ void hist_kernel(const int* __restrict__ dst, int* __restrict__ counts) {
    int e = blockIdx.x * 256 + threadIdx.x;
    if (e < N_EDGES) atomicAdd(&counts[dst[e]], 1);
}

__global__ void scan_kernel(const int* __restrict__ counts, int* __restrict__ row_ptr) {
    __shared__ int buf[1024];
    __shared__ int carry;
    if (threadIdx.x == 0) carry = 0;
    __syncthreads();
    for (int base = 0; base < N_NODES; base += 1024) {
        int i = base + (int)threadIdx.x;
        int v = (i < N_NODES) ? counts[i] : 0;
        buf[threadIdx.x] = v;
        __syncthreads();
        for (int off = 1; off < 1024; off <<= 1) {
            int t = (threadIdx.x >= (unsigned)off) ? buf[threadIdx.x - off] : 0;
            __syncthreads();
            buf[threadIdx.x] += t;
            __syncthreads();
        }
        int incl = buf[threadIdx.x];
        int c = carry;
        if (i < N_NODES) row_ptr[i + 1] = c + incl;
        __syncthreads();
        if (threadIdx.x == 1023) carry = c + incl;
        __syncthreads();
    }
    if (threadIdx.x == 0) row_ptr[0] = 0;
}

__global__ void scatter_kernel(const int* __restrict__ src, const int* __restrict__ dst,
                               const int* __restrict__ row_ptr, int* __restrict__ cursor,
                               int* __restrict__ esrc) {
    int e = blockIdx.x * 256 + threadIdx.x;
    if (e < N_EDGES) {
        int d = dst[e];
        int pos = row_ptr[d] + atomicAdd(&cursor[d], 1);
        esrc[pos] = src[e];
    }
}

// ---------------- conversions ----------------

__global__ void cvt_x_kernel(const float* __restrict__ x, _Float16* __restrict__ x16) {
    int t = blockIdx.x * 256 + threadIdx.x;
    if (t < N_NODES * F_INPUT / 4) {
        f32x4 v = *(const f32x4*)&x[t * 4];
        half4 h = {(_Float16)v.x, (_Float16)v.y, (_Float16)v.z, (_Float16)v.w};
        *(half4*)&x16[(size_t)t * 4] = h;
    }
}

// W [K x 256] fp32 -> Wt [256 x K] fp16
__global__ void wt_kernel(const float* __restrict__ W, _Float16* __restrict__ Wt, int K) {
    int t = blockIdx.x * 256 + threadIdx.x;
    if (t < K * HID) {
        int k = t >> 8;
        int c = t & 255;
        Wt[(size_t)c * K + k] = (_Float16)W[t];
    }
}

// ---------------- MFMA GEMM: C[M x 256] = A16[M x K] * Wt^T, fp16 in fp32 acc ----------------
// block: 64 rows x 256 cols, 4 waves; wave w covers cols [w*64, w*64+64).
// LDS is frag-major: each lane's 16B frag chunk staged at base + lane*16 via global_load_lds.

__device__ __forceinline__ void gl2lds16(const void* g, void* l) {
    __builtin_amdgcn_global_load_lds((const __attribute__((address_space(1))) void*)g,
                                     (__attribute__((address_space(3))) void*)l, 16, 0, 0);
}

__global__ __launch_bounds__(256) void mfma_gemm(const _Float16* __restrict__ A16,
                                                 const _Float16* __restrict__ Wt,
                                                 _Float16* __restrict__ out16,
                                                 float* __restrict__ out32,
                                                 int K) {
    __shared__ __align__(16) _Float16 As[4 * 512];    // 4 m-tiles x (64 lanes x 8 halves)
    __shared__ __align__(16) _Float16 Ws[16 * 512];   // 16 n-tiles x (64 lanes x 8 halves)
    int tid = threadIdx.x;
    int w = tid >> 6;
    int lane = tid & 63;
    int lrow = lane & 15;     // row (A) / col (B) within 16-tile
    int lk = lane >> 4;       // k quad
    int row0 = blockIdx.x * 64;

    f32x4 acc[4][4] = {};

    const _Float16* Abase = A16 + (size_t)(row0 + w * 16 + lrow) * K + lk * 8;

    for (int k0 = 0; k0 < K; k0 += 32) {
        // stage A m-tile w (lane's own frag bytes)
        gl2lds16(Abase + k0, &As[w * 512]);
        // stage 4 of the 16 W n-tiles
#pragma unroll
        for (int i = 0; i < 4; i++) {
            int tt = i * 4 + w;
            gl2lds16(Wt + (size_t)(tt * 16 + lrow) * K + k0 + lk * 8, &Ws[tt * 512]);
        }
        __syncthreads();
        half8 a[4], b[4];
#pragma unroll
        for (int m = 0; m < 4; m++) a[m] = *(const half8*)&As[m * 512 + lane * 8];
#pragma unroll
        for (int j = 0; j < 4; j++) b[j] = *(const half8*)&Ws[(w * 4 + j) * 512 + lane * 8];
#pragma unroll
        for (int m = 0; m < 4; m++)
#pragma unroll
            for (int j = 0; j < 4; j++)
                acc[m][j] = __builtin_amdgcn_mfma_f32_16x16x32_f16(a[m], b[j], acc[m][j], 0, 0, 0);
        __syncthreads();
    }

    // C/D layout: col = lane&15, row = (lane>>4)*4 + r
#pragma unroll
    for (int m = 0; m < 4; m++) {
#pragma unroll
        for (int r = 0; r < 4; r++) {
            int grow = row0 + m * 16 + lk * 4 + r;
            if (grow < N_NODES) {
                if (out16) {
#pragma unroll
                    for (int j = 0; j < 4; j++)
                        out16[(size_t)grow * HID + w * 64 + j * 16 + lrow] = (_Float16)acc[m][j][r];
                } else {
#pragma unroll
                    for (int j = 0; j < 4; j++)
                        out32[(size_t)grow * HID + w * 64 + j * 16 + lrow] = acc[m][j][r];
                }
            }
        }
    }
}

// ---------------- el/er ----------------
// one wave per node; lane covers dims lane*4..lane*4+3 (head = lane>>4).

__global__ __launch_bounds__(256) void elr_kernel(const _Float16* __restrict__ feat16,
                                                  const float* __restrict__ al,
                                                  const float* __restrict__ ar,
                                                  float* __restrict__ el, float* __restrict__ er) {
    int n = blockIdx.x * 4 + (threadIdx.x >> 6);
    int lane = threadIdx.x & 63;
    half4 f = *(const half4*)&feat16[(size_t)n * HID + lane * 4];
    f32x4 a = *(const f32x4*)&al[lane * 4];
    f32x4 r = *(const f32x4*)&ar[lane * 4];
    float pl = (float)f.x * a.x + (float)f.y * a.y + (float)f.z * a.z + (float)f.w * a.w;
    float pr = (float)f.x * r.x + (float)f.y * r.y + (float)f.z * r.z + (float)f.w * r.w;
#pragma unroll
    for (int off = 1; off < 16; off <<= 1) {
        pl += __shfl_xor(pl, off, 64);
        pr += __shfl_xor(pr, off, 64);
    }
    if ((lane & 15) == 0) {
        int h = lane >> 4;
        el[n * HEADS + h] = pl;
        er[n * HEADS + h] = pr;
    }
}

// ---------------- softmax + aggregation + epilogue ----------------
// one wave per node (4 nodes per 256-thread block). lane covers dims lane*4..+3, head = lane>>4.
// Online softmax across 64-edge chunks; logits + src stashed in LDS (stride 5, conflict-free).

__global__ __launch_bounds__(256) void agg_kernel(const _Float16* __restrict__ feat16,
                                                  const float* __restrict__ el,
                                                  const float* __restrict__ er,
                                                  const int* __restrict__ row_ptr,
                                                  const int* __restrict__ esrc,
                                                  const float* __restrict__ res,
                                                  const float* __restrict__ bias,
                                                  float* __restrict__ out32,
                                                  _Float16* __restrict__ out16,
                                                  float* __restrict__ outmean,
                                                  int do_relu) {
    __shared__ float lds[4][64 * 5];
    int wv = threadIdx.x >> 6;
    int lane = threadIdx.x & 63;
    int n = blockIdx.x * 4 + wv;
    int head = lane >> 4;
    int start = row_ptr[n];
    int deg = row_ptr[n + 1] - start;
    f32x4 ern = *(const f32x4*)&er[n * 4];
    float* L = lds[wv];

    f32x4 mx = {-1e30f, -1e30f, -1e30f, -1e30f};
    f32x4 acc = {0.f, 0.f, 0.f, 0.f};
    float smh = 0.f;

    for (int base = 0; base < deg; base += 64) {
        int e = base + lane;
        int s = 0;
        f32x4 x = {-1e30f, -1e30f, -1e30f, -1e30f};
        if (e < deg) {
            s = esrc[start + e];
            f32x4 v = *(const f32x4*)&el[s * 4];
            v = v + ern;
            x.x = v.x > 0.f ? v.x : 0.2f * v.x;
            x.y = v.y > 0.f ? v.y : 0.2f * v.y;
            x.z = v.z > 0.f ? v.z : 0.2f * v.z;
            x.w = v.w > 0.f ? v.w : 0.2f * v.w;
        }
        L[lane * 5 + 0] = x.x;
        L[lane * 5 + 1] = x.y;
        L[lane * 5 + 2] = x.z;
        L[lane * 5 + 3] = x.w;
        L[lane * 5 + 4] = __int_as_float(s);
        // chunk max (per head component) over 64 lanes
        f32x4 cm = x;
#pragma unroll
        for (int off = 1; off < 64; off <<= 1) {
            cm.x = fmaxf(cm.x, __shfl_xor(cm.x, off, 64));
            cm.y = fmaxf(cm.y, __shfl_xor(cm.y, off, 64));
            cm.z = fmaxf(cm.z, __shfl_xor(cm.z, off, 64));
            cm.w = fmaxf(cm.w, __shfl_xor(cm.w, off, 64));
        }
        f32x4 nmx;
        nmx.x = fmaxf(mx.x, cm.x);
        nmx.y = fmaxf(mx.y, cm.y);
        nmx.z = fmaxf(mx.z, cm.z);
        nmx.w = fmaxf(mx.w, cm.w);
        float mxh = (head == 0) ? mx.x : (head == 1) ? mx.y : (head == 2) ? mx.z : mx.w;
        float nmxh = (head == 0) ? nmx.x : (head == 1) ? nmx.y : (head == 2) ? nmx.z : nmx.w;
        float sc = __expf(mxh - nmxh);
        smh *= sc;
        acc = acc * sc;
        int cnt = min(64, deg - base);
        for (int j = 0; j < cnt; j++) {
            float xu = L[j * 5 + head];          // broadcast within head group
            int ss = __float_as_int(L[j * 5 + 4]);
            float ex = __expf(xu - nmxh);
            smh += ex;
            half4 f = *(const half4*)&feat16[(size_t)ss * HID + lane * 4];
            acc.x += ex * (float)f.x;
            acc.y += ex * (float)f.y;
            acc.z += ex * (float)f.z;
            acc.w += ex * (float)f.w;
        }
        mx = nmx;
    }

    float inv = 1.f / fmaxf(smh, 1e-16f);
    f32x4 o = acc * inv;
    o = o + *(const f32x4*)&res[(size_t)n * HID + lane * 4] + *(const f32x4*)&bias[lane * 4];
    if (do_relu) {
        o.x = fmaxf(o.x, 0.f);
        o.y = fmaxf(o.y, 0.f);
        o.z = fmaxf(o.z, 0.f);
        o.w = fmaxf(o.w, 0.f);
    }
    if (outmean) {
        // mean over heads: sum across lanes differing in bits 4,5
        o.x += __shfl_xor(o.x, 16, 64); o.x += __shfl_xor(o.x, 32, 64);
        o.y += __shfl_xor(o.y, 16, 64); o.y += __shfl_xor(o.y, 32, 64);
        o.z += __shfl_xor(o.z, 16, 64); o.z += __shfl_xor(o.z, 32, 64);
        o.w += __shfl_xor(o.w, 16, 64); o.w += __shfl_xor(o.w, 32, 64);
        if (head == 0) {
            f32x4 mo = o * 0.25f;
            *(f32x4*)&outmean[(size_t)n * DHID + (lane & 15) * 4] = mo;
        }
    } else {
        *(f32x4*)&out32[(size_t)n * HID + lane * 4] = o;
        half4 h = {(_Float16)o.x, (_Float16)o.y, (_Float16)o.z, (_Float16)o.w};
        *(half4*)&out16[(size_t)n * HID + lane * 4] = h;
    }
}

// ---------------- launch ----------------

extern "C" void kernel_launch(void* const* d_in, const int* in_sizes, int n_in,
                              void* d_out, int out_size, void* d_ws, size_t ws_size,
                              hipStream_t stream) {
    const float* x     = (const float*)d_in[0];
    const int*   ei    = (const int*)d_in[1];
    const float* W0    = (const float*)d_in[2];
    const float* W1    = (const float*)d_in[3];
    const float* W2    = (const float*)d_in[4];
    const float* al0   = (const float*)d_in[5];
    const float* al1   = (const float*)d_in[6];
    const float* al2   = (const float*)d_in[7];
    const float* ar0   = (const float*)d_in[8];
    const float* ar1   = (const float*)d_in[9];
    const float* ar2   = (const float*)d_in[10];
    const float* b0    = (const float*)d_in[11];
    const float* b1    = (const float*)d_in[12];
    const float* b2    = (const float*)d_in[13];
    const float* resW0 = (const float*)d_in[14];
    float* out = (float*)d_out;

    const int* srcp = ei;
    const int* dstp = ei + N_EDGES;

    char* p = (char*)d_ws;
    auto alloc = [&](size_t bytes) -> char* {
        char* r = p;
        p += (bytes + 255) & ~(size_t)255;
        return r;
    };
    float*     H32    = (float*)alloc((size_t)N_NODES * HID * 4);      // residual / fp32 h
    _Float16*  H16    = (_Float16*)alloc((size_t)M_PAD * HID * 2);     // fp16 h (GEMM input)
    _Float16*  feat16 = (_Float16*)alloc((size_t)M_PAD * HID * 2);     // GEMM output
    _Float16*  x16    = (_Float16*)alloc((size_t)M_PAD * F_INPUT * 2);
    float*     el     = (float*)alloc((size_t)N_NODES * HEADS * 4);
    float*     er     = (float*)alloc((size_t)N_NODES * HEADS * 4);
    _Float16*  Wt0    = (_Float16*)alloc((size_t)HID * F_INPUT * 2);
    _Float16*  WtR    = (_Float16*)alloc((size_t)HID * F_INPUT * 2);
    _Float16*  Wt1    = (_Float16*)alloc((size_t)HID * HID * 2);
    _Float16*  Wt2    = (_Float16*)alloc((size_t)HID * HID * 2);
    int*       counts = (int*)alloc((size_t)N_NODES * 4);
    int*       rowptr = (int*)alloc((size_t)(N_NODES + 1) * 4);
    int*       esrc   = (int*)alloc((size_t)N_EDGES * 4);

    const int EB = (N_EDGES + 255) / 256;
    const int GB = M_PAD / 64;        // 782
    const int NB = N_NODES / 4;       // 12500

    // CSR by dst
    hipMemsetAsync(counts, 0, (size_t)N_NODES * 4, stream);
    hist_kernel<<<EB, 256, 0, stream>>>(dstp, counts);
    scan_kernel<<<1, 1024, 0, stream>>>(counts, rowptr);
    hipMemsetAsync(counts, 0, (size_t)N_NODES * 4, stream);
    scatter_kernel<<<EB, 256, 0, stream>>>(srcp, dstp, rowptr, counts, esrc);

    // conversions
    cvt_x_kernel<<<(N_NODES * F_INPUT / 4 + 255) / 256, 256, 0, stream>>>(x, x16);
    wt_kernel<<<F_INPUT, 256, 0, stream>>>(W0, Wt0, F_INPUT);
    wt_kernel<<<F_INPUT, 256, 0, stream>>>(resW0, WtR, F_INPUT);
    wt_kernel<<<HID, 256, 0, stream>>>(W1, Wt1, HID);
    wt_kernel<<<HID, 256, 0, stream>>>(W2, Wt2, HID);

    // layer 0
    mfma_gemm<<<GB, 256, 0, stream>>>(x16, WtR, nullptr, H32, F_INPUT);   // res0 fp32
    mfma_gemm<<<GB, 256, 0, stream>>>(x16, Wt0, feat16, nullptr, F_INPUT);
    elr_kernel<<<NB, 256, 0, stream>>>(feat16, al0, ar0, el, er);
    agg_kernel<<<NB, 256, 0, stream>>>(feat16, el, er, rowptr, esrc, H32, b0, H32, H16, nullptr, 1);

    // layer 1
    mfma_gemm<<<GB, 256, 0, stream>>>(H16, Wt1, feat16, nullptr, HID);
    elr_kernel<<<NB, 256, 0, stream>>>(feat16, al1, ar1, el, er);
    agg_kernel<<<NB, 256, 0, stream>>>(feat16, el, er, rowptr, esrc, H32, b1, H32, H16, nullptr, 1);

    // layer 2 (mean over heads -> d_out)
    mfma_gemm<<<GB, 256, 0, stream>>>(H16, Wt2, feat16, nullptr, HID);
    elr_kernel<<<NB, 256, 0, stream>>>(feat16, al2, ar2, el, er);
    agg_kernel<<<NB, 256, 0, stream>>>(feat16, el, er, rowptr, esrc, H32, b2, nullptr, nullptr, out, 0);
}

// Round 3
// 549.168 us; speedup vs baseline: 2.4487x; 1.1080x over previous
//
#include <hip/hip_runtime.h>
#include <math.h>

#define N_NODES 50000
#define N_EDGES 800000
#define F_INPUT 128
#define HEADS 4
#define DHID 64
#define HID 256          // HEADS*DHID
#define M_PAD 50048      // 782 * 64 (GEMM row-tile padding)
#define SCAN_B 49        // ceil(50000/1024)

typedef _Float16 half8 __attribute__((ext_vector_type(8)));
typedef _Float16 half4 __attribute__((ext_vector_type(4)));
typedef float f32x4 __attribute__((ext_vector_type(4)));

// ---------------- CSR build ----------------

__global__ void hist_kernel(const int* __restrict__ dst, int* __restrict__ counts) {
    int e = blockIdx.x * 256 + threadIdx.x;
    if (e < N_EDGES) atomicAdd(&counts[dst[e]], 1);
}

// phase 1: per-block (1024 elems) inclusive prefix + block total
__global__ __launch_bounds__(256) void scan1_kernel(const int* __restrict__ counts,
                                                    int* __restrict__ pre,
                                                    int* __restrict__ bsum) {
    __shared__ int buf[256];
    int tid = threadIdx.x;
    int idx = blockIdx.x * 1024 + tid * 4;
    int v0 = 0, v1 = 0, v2 = 0, v3 = 0;
    if (idx + 3 < N_NODES) {
        int4 v = *(const int4*)&counts[idx];
        v0 = v.x; v1 = v.y; v2 = v.z; v3 = v.w;
    } else {
        if (idx + 0 < N_NODES) v0 = counts[idx + 0];
        if (idx + 1 < N_NODES) v1 = counts[idx + 1];
        if (idx + 2 < N_NODES) v2 = counts[idx + 2];
        if (idx + 3 < N_NODES) v3 = counts[idx + 3];
    }
    int s0 = v0, s1 = s0 + v1, s2 = s1 + v2, s3 = s2 + v3;
    buf[tid] = s3;
    __syncthreads();
    for (int off = 1; off < 256; off <<= 1) {
        int t = (tid >= off) ? buf[tid - off] : 0;
        __syncthreads();
        buf[tid] += t;
        __syncthreads();
    }
    int excl = buf[tid] - s3;
    if (idx + 0 < N_NODES) pre[idx + 0] = excl + s0;
    if (idx + 1 < N_NODES) pre[idx + 1] = excl + s1;
    if (idx + 2 < N_NODES) pre[idx + 2] = excl + s2;
    if (idx + 3 < N_NODES) pre[idx + 3] = excl + s3;
    if (tid == 255) bsum[blockIdx.x] = buf[255];
}

// phase 2: one wave scans the block sums (SCAN_B <= 64)
__global__ void scan2_kernel(const int* __restrict__ bsum, int* __restrict__ bpre) {
    int lane = threadIdx.x;
    int v = (lane < SCAN_B) ? bsum[lane] : 0;
    int orig = v;
#pragma unroll
    for (int off = 1; off < 64; off <<= 1) {
        int t = __shfl_up(v, off, 64);
        if (lane >= off) v += t;
    }
    if (lane < SCAN_B) bpre[lane] = v - orig;   // exclusive
}

// phase 3: row_ptr[i+1] = pre[i] + bpre[block]
__global__ __launch_bounds__(256) void scan3_kernel(const int* __restrict__ pre,
                                                    const int* __restrict__ bpre,
                                                    int* __restrict__ row_ptr) {
    int add = bpre[blockIdx.x];
    int idx = blockIdx.x * 1024 + threadIdx.x * 4;
#pragma unroll
    for (int u = 0; u < 4; u++) {
        int i = idx + u;
        if (i < N_NODES) row_ptr[i + 1] = pre[i] + add;
    }
    if (blockIdx.x == 0 && threadIdx.x == 0) row_ptr[0] = 0;
}

__global__ void scatter_kernel(const int* __restrict__ src, const int* __restrict__ dst,
                               const int* __restrict__ row_ptr, int* __restrict__ cursor,
                               int* __restrict__ esrc) {
    int e = blockIdx.x * 256 + threadIdx.x;
    if (e < N_EDGES) {
        int d = dst[e];
        int pos = row_ptr[d] + atomicAdd(&cursor[d], 1);
        esrc[pos] = src[e];
    }
}

// ---------------- conversions ----------------

__global__ void cvt_x_kernel(const float* __restrict__ x, _Float16* __restrict__ x16) {
    int t = blockIdx.x * 256 + threadIdx.x;
    if (t < N_NODES * F_INPUT / 4) {
        f32x4 v = *(const f32x4*)&x[t * 4];
        half4 h = {(_Float16)v.x, (_Float16)v.y, (_Float16)v.z, (_Float16)v.w};
        *(half4*)&x16[(size_t)t * 4] = h;
    }
}

// all four weight transposes in one kernel: W [K x 256] fp32 -> Wt [256 x K] fp16
__global__ void wt_all_kernel(const float* __restrict__ W0, _Float16* __restrict__ Wt0,
                              const float* __restrict__ WR, _Float16* __restrict__ WtR,
                              const float* __restrict__ W1, _Float16* __restrict__ Wt1,
                              const float* __restrict__ W2, _Float16* __restrict__ Wt2) {
    int t = blockIdx.x * 256 + threadIdx.x;
    const float* W; _Float16* Wt; int K; int u;
    if (t < 32768)        { W = W0; Wt = Wt0; K = F_INPUT; u = t; }
    else if (t < 65536)   { W = WR; Wt = WtR; K = F_INPUT; u = t - 32768; }
    else if (t < 131072)  { W = W1; Wt = Wt1; K = HID;     u = t - 65536; }
    else if (t < 196608)  { W = W2; Wt = Wt2; K = HID;     u = t - 131072; }
    else return;
    int k = u >> 8;
    int c = u & 255;
    Wt[(size_t)c * K + k] = (_Float16)W[u];
}

// ---------------- MFMA GEMM: C[M x 256] = A16[M x K] * Wt^T, fp16 in fp32 acc ----------------

__device__ __forceinline__ void gl2lds16(const void* g, void* l) {
    __builtin_amdgcn_global_load_lds((const __attribute__((address_space(1))) void*)g,
                                     (__attribute__((address_space(3))) void*)l, 16, 0, 0);
}

__global__ __launch_bounds__(256) void mfma_gemm(const _Float16* __restrict__ A16,
                                                 const _Float16* __restrict__ Wt,
                                                 _Float16* __restrict__ out16,
                                                 float* __restrict__ out32,
                                                 int K) {
    __shared__ __align__(16) _Float16 As[4 * 512];
    __shared__ __align__(16) _Float16 Ws[16 * 512];
    int tid = threadIdx.x;
    int w = tid >> 6;
    int lane = tid & 63;
    int lrow = lane & 15;
    int lk = lane >> 4;
    int row0 = blockIdx.x * 64;

    f32x4 acc[4][4] = {};
    const _Float16* Abase = A16 + (size_t)(row0 + w * 16 + lrow) * K + lk * 8;

    for (int k0 = 0; k0 < K; k0 += 32) {
        gl2lds16(Abase + k0, &As[w * 512]);
#pragma unroll
        for (int i = 0; i < 4; i++) {
            int tt = i * 4 + w;
            gl2lds16(Wt + (size_t)(tt * 16 + lrow) * K + k0 + lk * 8, &Ws[tt * 512]);
        }
        __syncthreads();
        half8 a[4], b[4];
#pragma unroll
        for (int m = 0; m < 4; m++) a[m] = *(const half8*)&As[m * 512 + lane * 8];
#pragma unroll
        for (int j = 0; j < 4; j++) b[j] = *(const half8*)&Ws[(w * 4 + j) * 512 + lane * 8];
#pragma unroll
        for (int m = 0; m < 4; m++)
#pragma unroll
            for (int j = 0; j < 4; j++)
                acc[m][j] = __builtin_amdgcn_mfma_f32_16x16x32_f16(a[m], b[j], acc[m][j], 0, 0, 0);
        __syncthreads();
    }

#pragma unroll
    for (int m = 0; m < 4; m++) {
#pragma unroll
        for (int r = 0; r < 4; r++) {
            int grow = row0 + m * 16 + lk * 4 + r;
            if (grow < N_NODES) {
                if (out16) {
#pragma unroll
                    for (int j = 0; j < 4; j++)
                        out16[(size_t)grow * HID + w * 64 + j * 16 + lrow] = (_Float16)acc[m][j][r];
                } else {
#pragma unroll
                    for (int j = 0; j < 4; j++)
                        out32[(size_t)grow * HID + w * 64 + j * 16 + lrow] = acc[m][j][r];
                }
            }
        }
    }
}

// ---------------- el/er ----------------

__global__ __launch_bounds__(256) void elr_kernel(const _Float16* __restrict__ feat16,
                                                  const float* __restrict__ al,
                                                  const float* __restrict__ ar,
                                                  float* __restrict__ el, float* __restrict__ er) {
    int n = blockIdx.x * 4 + (threadIdx.x >> 6);
    int lane = threadIdx.x & 63;
    half4 f = *(const half4*)&feat16[(size_t)n * HID + lane * 4];
    f32x4 a = *(const f32x4*)&al[lane * 4];
    f32x4 r = *(const f32x4*)&ar[lane * 4];
    float pl = (float)f.x * a.x + (float)f.y * a.y + (float)f.z * a.z + (float)f.w * a.w;
    float pr = (float)f.x * r.x + (float)f.y * r.y + (float)f.z * r.z + (float)f.w * r.w;
#pragma unroll
    for (int off = 1; off < 16; off <<= 1) {
        pl += __shfl_xor(pl, off, 64);
        pr += __shfl_xor(pr, off, 64);
    }
    if ((lane & 15) == 0) {
        int h = lane >> 4;
        el[n * HEADS + h] = pl;
        er[n * HEADS + h] = pr;
    }
}

// ---------------- softmax + aggregation + epilogue ----------------
// one wave per node; lane covers dims lane*4..+3, head = lane>>4.
// Per chunk: exp computed ONCE per lane (4 heads), stashed in LDS; denom via wave
// reduction; inner j-loop is 2 LDS reads + half4 gather + 4 FMA, unrolled x4.

__global__ __launch_bounds__(256) void agg_kernel(const _Float16* __restrict__ feat16,
                                                  const float* __restrict__ el,
                                                  const float* __restrict__ er,
                                                  const int* __restrict__ row_ptr,
                                                  const int* __restrict__ esrc,
                                                  const float* __restrict__ res,
                                                  const float* __restrict__ bias,
                                                  float* __restrict__ out32,
                                                  _Float16* __restrict__ out16,
                                                  float* __restrict__ outmean,
                                                  int do_relu) {
    __shared__ float lds[4][64 * 5];
    int wv = threadIdx.x >> 6;
    int lane = threadIdx.x & 63;
    int n = blockIdx.x * 4 + wv;
    int head = lane >> 4;
    int start = row_ptr[n];
    int deg = row_ptr[n + 1] - start;
    f32x4 ern = *(const f32x4*)&er[n * 4];
    float* L = lds[wv];

    f32x4 mx = {-1e30f, -1e30f, -1e30f, -1e30f};
    f32x4 acc = {0.f, 0.f, 0.f, 0.f};
    float smh = 0.f;

    for (int base = 0; base < deg; base += 64) {
        int e = base + lane;
        int s = 0;
        f32x4 x = {-1e30f, -1e30f, -1e30f, -1e30f};
        if (e < deg) {
            s = esrc[start + e];
            f32x4 v = *(const f32x4*)&el[s * 4];
            v = v + ern;
            x.x = v.x > 0.f ? v.x : 0.2f * v.x;
            x.y = v.y > 0.f ? v.y : 0.2f * v.y;
            x.z = v.z > 0.f ? v.z : 0.2f * v.z;
            x.w = v.w > 0.f ? v.w : 0.2f * v.w;
        }
        // chunk max
        f32x4 cm = x;
#pragma unroll
        for (int off = 1; off < 64; off <<= 1) {
            cm.x = fmaxf(cm.x, __shfl_xor(cm.x, off, 64));
            cm.y = fmaxf(cm.y, __shfl_xor(cm.y, off, 64));
            cm.z = fmaxf(cm.z, __shfl_xor(cm.z, off, 64));
            cm.w = fmaxf(cm.w, __shfl_xor(cm.w, off, 64));
        }
        f32x4 nmx;
        nmx.x = fmaxf(mx.x, cm.x);
        nmx.y = fmaxf(mx.y, cm.y);
        nmx.z = fmaxf(mx.z, cm.z);
        nmx.w = fmaxf(mx.w, cm.w);
        float mxh  = (head == 0) ? mx.x  : (head == 1) ? mx.y  : (head == 2) ? mx.z  : mx.w;
        float nmxh = (head == 0) ? nmx.x : (head == 1) ? nmx.y : (head == 2) ? nmx.z : nmx.w;
        float sc = __expf(mxh - nmxh);
        smh *= sc;
        acc = acc * sc;
        // exp once per lane (4 heads); invalid lanes give exp(-inf)=0
        f32x4 ex4;
        ex4.x = __expf(x.x - nmx.x);
        ex4.y = __expf(x.y - nmx.y);
        ex4.z = __expf(x.z - nmx.z);
        ex4.w = __expf(x.w - nmx.w);
        L[lane * 5 + 0] = ex4.x;
        L[lane * 5 + 1] = ex4.y;
        L[lane * 5 + 2] = ex4.z;
        L[lane * 5 + 3] = ex4.w;
        L[lane * 5 + 4] = __int_as_float(s);
        // chunk denom
        f32x4 cs = ex4;
#pragma unroll
        for (int off = 1; off < 64; off <<= 1) {
            cs.x += __shfl_xor(cs.x, off, 64);
            cs.y += __shfl_xor(cs.y, off, 64);
            cs.z += __shfl_xor(cs.z, off, 64);
            cs.w += __shfl_xor(cs.w, off, 64);
        }
        smh += (head == 0) ? cs.x : (head == 1) ? cs.y : (head == 2) ? cs.z : cs.w;

        int cnt = min(64, deg - base);
        int j = 0;
        for (; j + 4 <= cnt; j += 4) {
            float exv[4]; int ssv[4];
#pragma unroll
            for (int u = 0; u < 4; u++) {
                exv[u] = L[(j + u) * 5 + head];
                ssv[u] = __float_as_int(L[(j + u) * 5 + 4]);
            }
            half4 f[4];
#pragma unroll
            for (int u = 0; u < 4; u++)
                f[u] = *(const half4*)&feat16[(size_t)ssv[u] * HID + lane * 4];
#pragma unroll
            for (int u = 0; u < 4; u++) {
                acc.x += exv[u] * (float)f[u].x;
                acc.y += exv[u] * (float)f[u].y;
                acc.z += exv[u] * (float)f[u].z;
                acc.w += exv[u] * (float)f[u].w;
            }
        }
        for (; j < cnt; j++) {
            float ex = L[j * 5 + head];
            int ss = __float_as_int(L[j * 5 + 4]);
            half4 f = *(const half4*)&feat16[(size_t)ss * HID + lane * 4];
            acc.x += ex * (float)f.x;
            acc.y += ex * (float)f.y;
            acc.z += ex * (float)f.z;
            acc.w += ex * (float)f.w;
        }
        mx = nmx;
    }

    float inv = 1.f / fmaxf(smh, 1e-16f);
    f32x4 o = acc * inv;
    o = o + *(const f32x4*)&res[(size_t)n * HID + lane * 4] + *(const f32x4*)&bias[lane * 4];
    if (do_relu) {
        o.x = fmaxf(o.x, 0.f);
        o.y = fmaxf(o.y, 0.f);
        o.z = fmaxf(o.z, 0.f);
        o.w = fmaxf(o.w, 0.f);
    }
    if (outmean) {
        o.x += __shfl_xor(o.x, 16, 64); o.x += __shfl_xor(o.x, 32, 64);
        o.y += __shfl_xor(o.y, 16, 64); o.y += __shfl_xor(o.y, 32, 64);
        o.z += __shfl_xor(o.z, 16, 64); o.z += __shfl_xor(o.z, 32, 64);
        o.w += __shfl_xor(o.w, 16, 64); o.w += __shfl_xor(o.w, 32, 64);
        if (head == 0) {
            f32x4 mo = o * 0.25f;
            *(f32x4*)&outmean[(size_t)n * DHID + (lane & 15) * 4] = mo;
        }
    } else {
        *(f32x4*)&out32[(size_t)n * HID + lane * 4] = o;
        half4 h = {(_Float16)o.x, (_Float16)o.y, (_Float16)o.z, (_Float16)o.w};
        *(half4*)&out16[(size_t)n * HID + lane * 4] = h;
    }
}

// ---------------- launch ----------------

extern "C" void kernel_launch(void* const* d_in, const int* in_sizes, int n_in,
                              void* d_out, int out_size, void* d_ws, size_t ws_size,
                              hipStream_t stream) {
    const float* x     = (const float*)d_in[0];
    const int*   ei    = (const int*)d_in[1];
    const float* W0    = (const float*)d_in[2];
    const float* W1    = (const float*)d_in[3];
    const float* W2    = (const float*)d_in[4];
    const float* al0   = (const float*)d_in[5];
    const float* al1   = (const float*)d_in[6];
    const float* al2   = (const float*)d_in[7];
    const float* ar0   = (const float*)d_in[8];
    const float* ar1   = (const float*)d_in[9];
    const float* ar2   = (const float*)d_in[10];
    const float* b0    = (const float*)d_in[11];
    const float* b1    = (const float*)d_in[12];
    const float* b2    = (const float*)d_in[13];
    const float* resW0 = (const float*)d_in[14];
    float* out = (float*)d_out;

    const int* srcp = ei;
    const int* dstp = ei + N_EDGES;

    char* p = (char*)d_ws;
    auto alloc = [&](size_t bytes) -> char* {
        char* r = p;
        p += (bytes + 255) & ~(size_t)255;
        return r;
    };
    float*     H32    = (float*)alloc((size_t)N_NODES * HID * 4);
    _Float16*  H16    = (_Float16*)alloc((size_t)M_PAD * HID * 2);
    _Float16*  feat16 = (_Float16*)alloc((size_t)M_PAD * HID * 2);
    _Float16*  x16    = (_Float16*)alloc((size_t)M_PAD * F_INPUT * 2);
    float*     el     = (float*)alloc((size_t)N_NODES * HEADS * 4);
    float*     er     = (float*)alloc((size_t)N_NODES * HEADS * 4);
    _Float16*  Wt0    = (_Float16*)alloc((size_t)HID * F_INPUT * 2);
    _Float16*  WtR    = (_Float16*)alloc((size_t)HID * F_INPUT * 2);
    _Float16*  Wt1    = (_Float16*)alloc((size_t)HID * HID * 2);
    _Float16*  Wt2    = (_Float16*)alloc((size_t)HID * HID * 2);
    int*       counts = (int*)alloc((size_t)N_NODES * 4);
    int*       rowptr = (int*)alloc((size_t)(N_NODES + 1) * 4);
    int*       esrc   = (int*)alloc((size_t)N_EDGES * 4);
    int*       pre    = (int*)alloc((size_t)N_NODES * 4);
    int*       bsum   = (int*)alloc((size_t)SCAN_B * 4);
    int*       bpre   = (int*)alloc((size_t)SCAN_B * 4);

    const int EB = (N_EDGES + 255) / 256;
    const int GB = M_PAD / 64;
    const int NB = N_NODES / 4;

    // CSR by dst
    hipMemsetAsync(counts, 0, (size_t)N_NODES * 4, stream);
    hist_kernel<<<EB, 256, 0, stream>>>(dstp, counts);
    scan1_kernel<<<SCAN_B, 256, 0, stream>>>(counts, pre, bsum);
    scan2_kernel<<<1, 64, 0, stream>>>(bsum, bpre);
    scan3_kernel<<<SCAN_B, 256, 0, stream>>>(pre, bpre, rowptr);
    hipMemsetAsync(counts, 0, (size_t)N_NODES * 4, stream);
    scatter_kernel<<<EB, 256, 0, stream>>>(srcp, dstp, rowptr, counts, esrc);

    // conversions
    cvt_x_kernel<<<(N_NODES * F_INPUT / 4 + 255) / 256, 256, 0, stream>>>(x, x16);
    wt_all_kernel<<<768, 256, 0, stream>>>(W0, Wt0, resW0, WtR, W1, Wt1, W2, Wt2);

    // layer 0
    mfma_gemm<<<GB, 256, 0, stream>>>(x16, WtR, nullptr, H32, F_INPUT);
    mfma_gemm<<<GB, 256, 0, stream>>>(x16, Wt0, feat16, nullptr, F_INPUT);
    elr_kernel<<<NB, 256, 0, stream>>>(feat16, al0, ar0, el, er);
    agg_kernel<<<NB, 256, 0, stream>>>(feat16, el, er, rowptr, esrc, H32, b0, H32, H16, nullptr, 1);

    // layer 1
    mfma_gemm<<<GB, 256, 0, stream>>>(H16, Wt1, feat16, nullptr, HID);
    elr_kernel<<<NB, 256, 0, stream>>>(feat16, al1, ar1, el, er);
    agg_kernel<<<NB, 256, 0, stream>>>(feat16, el, er, rowptr, esrc, H32, b1, H32, H16, nullptr, 1);

    // layer 2 (mean over heads -> d_out)
    mfma_gemm<<<GB, 256, 0, stream>>>(H16, Wt2, feat16, nullptr, HID);
    elr_kernel<<<NB, 256, 0, stream>>>(feat16, al2, ar2, el, er);
    agg_kernel<<<NB, 256, 0, stream>>>(feat16, el, er, rowptr, esrc, H32, b2, nullptr, nullptr, out, 0);
}

// Round 4
// 517.870 us; speedup vs baseline: 2.5967x; 1.0604x over previous
//
#include <hip/hip_runtime.h>
#include <math.h>

#define N_NODES 50000
#define N_EDGES 800000
#define F_INPUT 128
#define HEADS 4
#define DHID 64
#define HID 256          // HEADS*DHID
#define M_PAD 50048      // 782*64 = 391*128
#define SCAN_B 49        // ceil(50000/1024)

typedef _Float16 half8 __attribute__((ext_vector_type(8)));
typedef _Float16 half4 __attribute__((ext_vector_type(4)));
typedef float f32x4 __attribute__((ext_vector_type(4)));

// ---------------- CSR build ----------------

__global__ void hist_kernel(const int* __restrict__ dst, int* __restrict__ counts) {
    int e = blockIdx.x * 256 + threadIdx.x;
    if (e < N_EDGES) atomicAdd(&counts[dst[e]], 1);
}

__global__ __launch_bounds__(256) void scan1_kernel(const int* __restrict__ counts,
                                                    int* __restrict__ pre,
                                                    int* __restrict__ bsum) {
    __shared__ int buf[256];
    int tid = threadIdx.x;
    int idx = blockIdx.x * 1024 + tid * 4;
    int v0 = 0, v1 = 0, v2 = 0, v3 = 0;
    if (idx + 3 < N_NODES) {
        int4 v = *(const int4*)&counts[idx];
        v0 = v.x; v1 = v.y; v2 = v.z; v3 = v.w;
    } else {
        if (idx + 0 < N_NODES) v0 = counts[idx + 0];
        if (idx + 1 < N_NODES) v1 = counts[idx + 1];
        if (idx + 2 < N_NODES) v2 = counts[idx + 2];
    }
    int s0 = v0, s1 = s0 + v1, s2 = s1 + v2, s3 = s2 + v3;
    buf[tid] = s3;
    __syncthreads();
    for (int off = 1; off < 256; off <<= 1) {
        int t = (tid >= off) ? buf[tid - off] : 0;
        __syncthreads();
        buf[tid] += t;
        __syncthreads();
    }
    int excl = buf[tid] - s3;
    if (idx + 0 < N_NODES) pre[idx + 0] = excl + s0;
    if (idx + 1 < N_NODES) pre[idx + 1] = excl + s1;
    if (idx + 2 < N_NODES) pre[idx + 2] = excl + s2;
    if (idx + 3 < N_NODES) pre[idx + 3] = excl + s3;
    if (tid == 255) bsum[blockIdx.x] = buf[255];
}

__global__ void scan2_kernel(const int* __restrict__ bsum, int* __restrict__ bpre) {
    int lane = threadIdx.x;
    int v = (lane < SCAN_B) ? bsum[lane] : 0;
    int orig = v;
#pragma unroll
    for (int off = 1; off < 64; off <<= 1) {
        int t = __shfl_up(v, off, 64);
        if (lane >= off) v += t;
    }
    if (lane < SCAN_B) bpre[lane] = v - orig;
}

__global__ __launch_bounds__(256) void scan3_kernel(const int* __restrict__ pre,
                                                    const int* __restrict__ bpre,
                                                    int* __restrict__ row_ptr) {
    int add = bpre[blockIdx.x];
    int idx = blockIdx.x * 1024 + threadIdx.x * 4;
#pragma unroll
    for (int u = 0; u < 4; u++) {
        int i = idx + u;
        if (i < N_NODES) row_ptr[i + 1] = pre[i] + add;
    }
    if (blockIdx.x == 0 && threadIdx.x == 0) row_ptr[0] = 0;
}

__global__ void scatter_kernel(const int* __restrict__ src, const int* __restrict__ dst,
                               const int* __restrict__ row_ptr, int* __restrict__ cursor,
                               int* __restrict__ esrc) {
    int e = blockIdx.x * 256 + threadIdx.x;
    if (e < N_EDGES) {
        int d = dst[e];
        int pos = row_ptr[d] + atomicAdd(&cursor[d], 1);
        esrc[pos] = src[e];
    }
}

// ---------------- conversions ----------------

__global__ void cvt_x_kernel(const float* __restrict__ x, _Float16* __restrict__ x16) {
    int t = blockIdx.x * 256 + threadIdx.x;
    if (t < N_NODES * F_INPUT / 4) {
        f32x4 v = *(const f32x4*)&x[t * 4];
        half4 h = {(_Float16)v.x, (_Float16)v.y, (_Float16)v.z, (_Float16)v.w};
        *(half4*)&x16[(size_t)t * 4] = h;
    }
}

// WtL0 [512 x 128] = [W0 | resW0] transposed; Wt1/Wt2 [256 x 256]
__global__ void wt_all_kernel(const float* __restrict__ W0, const float* __restrict__ WR,
                              _Float16* __restrict__ WtL0,
                              const float* __restrict__ W1, _Float16* __restrict__ Wt1,
                              const float* __restrict__ W2, _Float16* __restrict__ Wt2) {
    int t = blockIdx.x * 256 + threadIdx.x;
    if (t < 65536) {
        int c = t >> 7;        // 0..511
        int k = t & 127;
        float v = (c < 256) ? W0[k * 256 + c] : WR[k * 256 + (c - 256)];
        WtL0[t] = (_Float16)v;
    } else if (t < 131072) {
        int u = t - 65536;
        int c = u >> 8;
        int k = u & 255;
        Wt1[u] = (_Float16)W1[k * 256 + c];
    } else if (t < 196608) {
        int u = t - 131072;
        int c = u >> 8;
        int k = u & 255;
        Wt2[u] = (_Float16)W2[k * 256 + c];
    }
}

// ---------------- MFMA GEMMs ----------------

__device__ __forceinline__ void gl2lds16(const void* g, void* l) {
    __builtin_amdgcn_global_load_lds((const __attribute__((address_space(1))) void*)g,
                                     (__attribute__((address_space(3))) void*)l, 16, 0, 0);
}

// layer 0: C[M x 512] = x16[M x 128] * WtL0^T. 64 rows x 512 cols per block, 8 waves.
// cols 0..255 -> feat16 (+ fused el/er), cols 256..511 -> res32 fp32.
__global__ __launch_bounds__(512) void gemm_l0(const _Float16* __restrict__ A16,
                                               const _Float16* __restrict__ WtL0,
                                               _Float16* __restrict__ feat16,
                                               float* __restrict__ res32,
                                               const float* __restrict__ al,
                                               const float* __restrict__ ar,
                                               float* __restrict__ el, float* __restrict__ er) {
    __shared__ __align__(16) _Float16 As[4 * 512];
    __shared__ __align__(16) _Float16 Ws[32 * 512];
    int tid = threadIdx.x;
    int w = tid >> 6;
    int lane = tid & 63;
    int lrow = lane & 15;
    int lk = lane >> 4;
    int row0 = blockIdx.x * 64;

    f32x4 acc[4][4] = {};

    for (int k0 = 0; k0 < F_INPUT; k0 += 32) {
        if (w < 4)
            gl2lds16(A16 + (size_t)(row0 + w * 16 + lrow) * F_INPUT + k0 + lk * 8, &As[w * 512]);
#pragma unroll
        for (int i = 0; i < 4; i++) {
            int tt = i * 8 + w;
            gl2lds16(WtL0 + (size_t)(tt * 16 + lrow) * F_INPUT + k0 + lk * 8, &Ws[tt * 512]);
        }
        __syncthreads();
        half8 a[4], b[4];
#pragma unroll
        for (int m = 0; m < 4; m++) a[m] = *(const half8*)&As[m * 512 + lane * 8];
#pragma unroll
        for (int j = 0; j < 4; j++) b[j] = *(const half8*)&Ws[(w * 4 + j) * 512 + lane * 8];
#pragma unroll
        for (int m = 0; m < 4; m++)
#pragma unroll
            for (int j = 0; j < 4; j++)
                acc[m][j] = __builtin_amdgcn_mfma_f32_16x16x32_f16(a[m], b[j], acc[m][j], 0, 0, 0);
        __syncthreads();
    }

    if (w < 4) {
        // feat + fused el/er (head = w)
        float alv[4], arv[4];
#pragma unroll
        for (int j = 0; j < 4; j++) {
            alv[j] = al[w * 64 + j * 16 + lrow];
            arv[j] = ar[w * 64 + j * 16 + lrow];
        }
#pragma unroll
        for (int m = 0; m < 4; m++) {
#pragma unroll
            for (int r = 0; r < 4; r++) {
                int row = row0 + m * 16 + lk * 4 + r;
                if (row < N_NODES) {
#pragma unroll
                    for (int j = 0; j < 4; j++)
                        feat16[(size_t)row * HID + w * 64 + j * 16 + lrow] = (_Float16)acc[m][j][r];
                }
                float pl = acc[m][0][r] * alv[0] + acc[m][1][r] * alv[1] +
                           acc[m][2][r] * alv[2] + acc[m][3][r] * alv[3];
                float pr = acc[m][0][r] * arv[0] + acc[m][1][r] * arv[1] +
                           acc[m][2][r] * arv[2] + acc[m][3][r] * arv[3];
#pragma unroll
                for (int off = 1; off < 16; off <<= 1) {
                    pl += __shfl_xor(pl, off, 64);
                    pr += __shfl_xor(pr, off, 64);
                }
                if (lrow == 0 && row < N_NODES) {
                    el[row * 4 + w] = pl;
                    er[row * 4 + w] = pr;
                }
            }
        }
    } else {
        int wc = w - 4;
#pragma unroll
        for (int m = 0; m < 4; m++) {
#pragma unroll
            for (int r = 0; r < 4; r++) {
                int row = row0 + m * 16 + lk * 4 + r;
                if (row < N_NODES) {
#pragma unroll
                    for (int j = 0; j < 4; j++)
                        res32[(size_t)row * HID + wc * 64 + j * 16 + lrow] = acc[m][j][r];
                }
            }
        }
    }
}

// layers 1/2: C[M x 256] = A16[M x 256] * Wt^T. 128 rows x 256 cols per block,
// 8 waves in 2(row)x4(col); fused el/er epilogue (head = wcol).
__global__ __launch_bounds__(512) void gemm_h(const _Float16* __restrict__ A16,
                                              const _Float16* __restrict__ Wt,
                                              _Float16* __restrict__ feat16,
                                              const float* __restrict__ al,
                                              const float* __restrict__ ar,
                                              float* __restrict__ el, float* __restrict__ er) {
    __shared__ __align__(16) _Float16 As[8 * 512];
    __shared__ __align__(16) _Float16 Ws[16 * 512];
    int tid = threadIdx.x;
    int w = tid >> 6;
    int lane = tid & 63;
    int lrow = lane & 15;
    int lk = lane >> 4;
    int wrow = w >> 2;
    int wcol = w & 3;
    int row0 = blockIdx.x * 128;

    f32x4 acc[4][4] = {};

    for (int k0 = 0; k0 < HID; k0 += 32) {
        gl2lds16(A16 + (size_t)(row0 + w * 16 + lrow) * HID + k0 + lk * 8, &As[w * 512]);
        gl2lds16(Wt + (size_t)(w * 16 + lrow) * HID + k0 + lk * 8, &Ws[w * 512]);
        gl2lds16(Wt + (size_t)((w + 8) * 16 + lrow) * HID + k0 + lk * 8, &Ws[(w + 8) * 512]);
        __syncthreads();
        half8 a[4], b[4];
#pragma unroll
        for (int m = 0; m < 4; m++) a[m] = *(const half8*)&As[(wrow * 4 + m) * 512 + lane * 8];
#pragma unroll
        for (int j = 0; j < 4; j++) b[j] = *(const half8*)&Ws[(wcol * 4 + j) * 512 + lane * 8];
#pragma unroll
        for (int m = 0; m < 4; m++)
#pragma unroll
            for (int j = 0; j < 4; j++)
                acc[m][j] = __builtin_amdgcn_mfma_f32_16x16x32_f16(a[m], b[j], acc[m][j], 0, 0, 0);
        __syncthreads();
    }

    float alv[4], arv[4];
#pragma unroll
    for (int j = 0; j < 4; j++) {
        alv[j] = al[wcol * 64 + j * 16 + lrow];
        arv[j] = ar[wcol * 64 + j * 16 + lrow];
    }
#pragma unroll
    for (int m = 0; m < 4; m++) {
#pragma unroll
        for (int r = 0; r < 4; r++) {
            int row = row0 + wrow * 64 + m * 16 + lk * 4 + r;
            if (row < N_NODES) {
#pragma unroll
                for (int j = 0; j < 4; j++)
                    feat16[(size_t)row * HID + wcol * 64 + j * 16 + lrow] = (_Float16)acc[m][j][r];
            }
            float pl = acc[m][0][r] * alv[0] + acc[m][1][r] * alv[1] +
                       acc[m][2][r] * alv[2] + acc[m][3][r] * alv[3];
            float pr = acc[m][0][r] * arv[0] + acc[m][1][r] * arv[1] +
                       acc[m][2][r] * arv[2] + acc[m][3][r] * arv[3];
#pragma unroll
            for (int off = 1; off < 16; off <<= 1) {
                pl += __shfl_xor(pl, off, 64);
                pr += __shfl_xor(pr, off, 64);
            }
            if (lrow == 0 && row < N_NODES) {
                el[row * 4 + wcol] = pl;
                er[row * 4 + wcol] = pr;
            }
        }
    }
}

// ---------------- softmax + aggregation + epilogue ----------------
// one wave per node; lane covers dims lane*4..+3, head = lane>>4.

__global__ __launch_bounds__(256) void agg_kernel(const _Float16* __restrict__ feat16,
                                                  const float* __restrict__ el,
                                                  const float* __restrict__ er,
                                                  const int* __restrict__ row_ptr,
                                                  const int* __restrict__ esrc,
                                                  const float* __restrict__ res,
                                                  const float* __restrict__ bias,
                                                  float* __restrict__ out32,
                                                  _Float16* __restrict__ out16,
                                                  float* __restrict__ outmean,
                                                  int do_relu) {
    __shared__ float lds[4][64 * 5];
    int wv = threadIdx.x >> 6;
    int lane = threadIdx.x & 63;
    int n = blockIdx.x * 4 + wv;
    int head = lane >> 4;
    int start = row_ptr[n];
    int deg = row_ptr[n + 1] - start;
    f32x4 ern = *(const f32x4*)&er[n * 4];
    float* L = lds[wv];

    f32x4 acc = {0.f, 0.f, 0.f, 0.f};
    float smh = 0.f;

    if (deg <= 64) {
        // fast path: single chunk, no online rescale
        int s = 0;
        f32x4 x = {-1e30f, -1e30f, -1e30f, -1e30f};
        if (lane < deg) {
            s = esrc[start + lane];
            f32x4 v = *(const f32x4*)&el[s * 4];
            v = v + ern;
            x.x = v.x > 0.f ? v.x : 0.2f * v.x;
            x.y = v.y > 0.f ? v.y : 0.2f * v.y;
            x.z = v.z > 0.f ? v.z : 0.2f * v.z;
            x.w = v.w > 0.f ? v.w : 0.2f * v.w;
        }
        f32x4 cm = x;
#pragma unroll
        for (int off = 1; off < 64; off <<= 1) {
            cm.x = fmaxf(cm.x, __shfl_xor(cm.x, off, 64));
            cm.y = fmaxf(cm.y, __shfl_xor(cm.y, off, 64));
            cm.z = fmaxf(cm.z, __shfl_xor(cm.z, off, 64));
            cm.w = fmaxf(cm.w, __shfl_xor(cm.w, off, 64));
        }
        f32x4 ex4;
        ex4.x = __expf(x.x - cm.x);
        ex4.y = __expf(x.y - cm.y);
        ex4.z = __expf(x.z - cm.z);
        ex4.w = __expf(x.w - cm.w);
        L[lane * 5 + 0] = ex4.x;
        L[lane * 5 + 1] = ex4.y;
        L[lane * 5 + 2] = ex4.z;
        L[lane * 5 + 3] = ex4.w;
        L[lane * 5 + 4] = __int_as_float(s);
        f32x4 cs = ex4;
#pragma unroll
        for (int off = 1; off < 64; off <<= 1) {
            cs.x += __shfl_xor(cs.x, off, 64);
            cs.y += __shfl_xor(cs.y, off, 64);
            cs.z += __shfl_xor(cs.z, off, 64);
            cs.w += __shfl_xor(cs.w, off, 64);
        }
        smh = (head == 0) ? cs.x : (head == 1) ? cs.y : (head == 2) ? cs.z : cs.w;

        int j = 0;
        for (; j + 4 <= deg; j += 4) {
            float exv[4]; int ssv[4];
#pragma unroll
            for (int u = 0; u < 4; u++) {
                exv[u] = L[(j + u) * 5 + head];
                ssv[u] = __float_as_int(L[(j + u) * 5 + 4]);
            }
            half4 f[4];
#pragma unroll
            for (int u = 0; u < 4; u++)
                f[u] = *(const half4*)&feat16[(size_t)ssv[u] * HID + lane * 4];
#pragma unroll
            for (int u = 0; u < 4; u++) {
                acc.x += exv[u] * (float)f[u].x;
                acc.y += exv[u] * (float)f[u].y;
                acc.z += exv[u] * (float)f[u].z;
                acc.w += exv[u] * (float)f[u].w;
            }
        }
        for (; j < deg; j++) {
            float ex = L[j * 5 + head];
            int ss = __float_as_int(L[j * 5 + 4]);
            half4 f = *(const half4*)&feat16[(size_t)ss * HID + lane * 4];
            acc.x += ex * (float)f.x;
            acc.y += ex * (float)f.y;
            acc.z += ex * (float)f.z;
            acc.w += ex * (float)f.w;
        }
    } else {
        // general path: online softmax over 64-edge chunks
        f32x4 mx = {-1e30f, -1e30f, -1e30f, -1e30f};
        for (int base = 0; base < deg; base += 64) {
            int e = base + lane;
            int s = 0;
            f32x4 x = {-1e30f, -1e30f, -1e30f, -1e30f};
            if (e < deg) {
                s = esrc[start + e];
                f32x4 v = *(const f32x4*)&el[s * 4];
                v = v + ern;
                x.x = v.x > 0.f ? v.x : 0.2f * v.x;
                x.y = v.y > 0.f ? v.y : 0.2f * v.y;
                x.z = v.z > 0.f ? v.z : 0.2f * v.z;
                x.w = v.w > 0.f ? v.w : 0.2f * v.w;
            }
            f32x4 cm = x;
#pragma unroll
            for (int off = 1; off < 64; off <<= 1) {
                cm.x = fmaxf(cm.x, __shfl_xor(cm.x, off, 64));
                cm.y = fmaxf(cm.y, __shfl_xor(cm.y, off, 64));
                cm.z = fmaxf(cm.z, __shfl_xor(cm.z, off, 64));
                cm.w = fmaxf(cm.w, __shfl_xor(cm.w, off, 64));
            }
            f32x4 nmx;
            nmx.x = fmaxf(mx.x, cm.x);
            nmx.y = fmaxf(mx.y, cm.y);
            nmx.z = fmaxf(mx.z, cm.z);
            nmx.w = fmaxf(mx.w, cm.w);
            float mxh  = (head == 0) ? mx.x  : (head == 1) ? mx.y  : (head == 2) ? mx.z  : mx.w;
            float nmxh = (head == 0) ? nmx.x : (head == 1) ? nmx.y : (head == 2) ? nmx.z : nmx.w;
            float sc = __expf(mxh - nmxh);
            smh *= sc;
            acc = acc * sc;
            f32x4 ex4;
            ex4.x = __expf(x.x - nmx.x);
            ex4.y = __expf(x.y - nmx.y);
            ex4.z = __expf(x.z - nmx.z);
            ex4.w = __expf(x.w - nmx.w);
            L[lane * 5 + 0] = ex4.x;
            L[lane * 5 + 1] = ex4.y;
            L[lane * 5 + 2] = ex4.z;
            L[lane * 5 + 3] = ex4.w;
            L[lane * 5 + 4] = __int_as_float(s);
            f32x4 cs = ex4;
#pragma unroll
            for (int off = 1; off < 64; off <<= 1) {
                cs.x += __shfl_xor(cs.x, off, 64);
                cs.y += __shfl_xor(cs.y, off, 64);
                cs.z += __shfl_xor(cs.z, off, 64);
                cs.w += __shfl_xor(cs.w, off, 64);
            }
            smh += (head == 0) ? cs.x : (head == 1) ? cs.y : (head == 2) ? cs.z : cs.w;

            int cnt = min(64, deg - base);
            int j = 0;
            for (; j + 4 <= cnt; j += 4) {
                float exv[4]; int ssv[4];
#pragma unroll
                for (int u = 0; u < 4; u++) {
                    exv[u] = L[(j + u) * 5 + head];
                    ssv[u] = __float_as_int(L[(j + u) * 5 + 4]);
                }
                half4 f[4];
#pragma unroll
                for (int u = 0; u < 4; u++)
                    f[u] = *(const half4*)&feat16[(size_t)ssv[u] * HID + lane * 4];
#pragma unroll
                for (int u = 0; u < 4; u++) {
                    acc.x += exv[u] * (float)f[u].x;
                    acc.y += exv[u] * (float)f[u].y;
                    acc.z += exv[u] * (float)f[u].z;
                    acc.w += exv[u] * (float)f[u].w;
                }
            }
            for (; j < cnt; j++) {
                float ex = L[j * 5 + head];
                int ss = __float_as_int(L[j * 5 + 4]);
                half4 f = *(const half4*)&feat16[(size_t)ss * HID + lane * 4];
                acc.x += ex * (float)f.x;
                acc.y += ex * (float)f.y;
                acc.z += ex * (float)f.z;
                acc.w += ex * (float)f.w;
            }
            mx = nmx;
        }
    }

    float inv = 1.f / fmaxf(smh, 1e-16f);
    f32x4 o = acc * inv;
    o = o + *(const f32x4*)&res[(size_t)n * HID + lane * 4] + *(const f32x4*)&bias[lane * 4];
    if (do_relu) {
        o.x = fmaxf(o.x, 0.f);
        o.y = fmaxf(o.y, 0.f);
        o.z = fmaxf(o.z, 0.f);
        o.w = fmaxf(o.w, 0.f);
    }
    if (outmean) {
        o.x += __shfl_xor(o.x, 16, 64); o.x += __shfl_xor(o.x, 32, 64);
        o.y += __shfl_xor(o.y, 16, 64); o.y += __shfl_xor(o.y, 32, 64);
        o.z += __shfl_xor(o.z, 16, 64); o.z += __shfl_xor(o.z, 32, 64);
        o.w += __shfl_xor(o.w, 16, 64); o.w += __shfl_xor(o.w, 32, 64);
        if (head == 0) {
            f32x4 mo = o * 0.25f;
            *(f32x4*)&outmean[(size_t)n * DHID + (lane & 15) * 4] = mo;
        }
    } else {
        *(f32x4*)&out32[(size_t)n * HID + lane * 4] = o;
        half4 h = {(_Float16)o.x, (_Float16)o.y, (_Float16)o.z, (_Float16)o.w};
        *(half4*)&out16[(size_t)n * HID + lane * 4] = h;
    }
}

// ---------------- launch ----------------

extern "C" void kernel_launch(void* const* d_in, const int* in_sizes, int n_in,
                              void* d_out, int out_size, void* d_ws, size_t ws_size,
                              hipStream_t stream) {
    const float* x     = (const float*)d_in[0];
    const int*   ei    = (const int*)d_in[1];
    const float* W0    = (const float*)d_in[2];
    const float* W1    = (const float*)d_in[3];
    const float* W2    = (const float*)d_in[4];
    const float* al0   = (const float*)d_in[5];
    const float* al1   = (const float*)d_in[6];
    const float* al2   = (const float*)d_in[7];
    const float* ar0   = (const float*)d_in[8];
    const float* ar1   = (const float*)d_in[9];
    const float* ar2   = (const float*)d_in[10];
    const float* b0    = (const float*)d_in[11];
    const float* b1    = (const float*)d_in[12];
    const float* b2    = (const float*)d_in[13];
    const float* resW0 = (const float*)d_in[14];
    float* out = (float*)d_out;

    const int* srcp = ei;
    const int* dstp = ei + N_EDGES;

    char* p = (char*)d_ws;
    auto alloc = [&](size_t bytes) -> char* {
        char* r = p;
        p += (bytes + 255) & ~(size_t)255;
        return r;
    };
    float*     H32    = (float*)alloc((size_t)N_NODES * HID * 4);
    _Float16*  H16    = (_Float16*)alloc((size_t)M_PAD * HID * 2);
    _Float16*  feat16 = (_Float16*)alloc((size_t)M_PAD * HID * 2);
    _Float16*  x16    = (_Float16*)alloc((size_t)M_PAD * F_INPUT * 2);
    float*     el     = (float*)alloc((size_t)N_NODES * HEADS * 4);
    float*     er     = (float*)alloc((size_t)N_NODES * HEADS * 4);
    _Float16*  WtL0   = (_Float16*)alloc((size_t)512 * F_INPUT * 2);
    _Float16*  Wt1    = (_Float16*)alloc((size_t)HID * HID * 2);
    _Float16*  Wt2    = (_Float16*)alloc((size_t)HID * HID * 2);
    int*       counts = (int*)alloc((size_t)2 * N_NODES * 4);   // counts + cursor (adjacent)
    int*       cursor = counts + N_NODES;
    int*       rowptr = (int*)alloc((size_t)(N_NODES + 1) * 4);
    int*       esrc   = (int*)alloc((size_t)N_EDGES * 4);
    int*       pre    = (int*)alloc((size_t)N_NODES * 4);
    int*       bsum   = (int*)alloc((size_t)SCAN_B * 4);
    int*       bpre   = (int*)alloc((size_t)SCAN_B * 4);

    const int EB = (N_EDGES + 255) / 256;
    const int NB = N_NODES / 4;

    // CSR by dst
    hipMemsetAsync(counts, 0, (size_t)2 * N_NODES * 4, stream);
    hist_kernel<<<EB, 256, 0, stream>>>(dstp, counts);
    scan1_kernel<<<SCAN_B, 256, 0, stream>>>(counts, pre, bsum);
    scan2_kernel<<<1, 64, 0, stream>>>(bsum, bpre);
    scan3_kernel<<<SCAN_B, 256, 0, stream>>>(pre, bpre, rowptr);
    scatter_kernel<<<EB, 256, 0, stream>>>(srcp, dstp, rowptr, cursor, esrc);

    // conversions
    cvt_x_kernel<<<(N_NODES * F_INPUT / 4 + 255) / 256, 256, 0, stream>>>(x, x16);
    wt_all_kernel<<<768, 256, 0, stream>>>(W0, resW0, WtL0, W1, Wt1, W2, Wt2);

    // layer 0: fused dual GEMM (feat + residual) with el/er epilogue
    gemm_l0<<<M_PAD / 64, 512, 0, stream>>>(x16, WtL0, feat16, H32, al0, ar0, el, er);
    agg_kernel<<<NB, 256, 0, stream>>>(feat16, el, er, rowptr, esrc, H32, b0, H32, H16, nullptr, 1);

    // layer 1
    gemm_h<<<M_PAD / 128, 512, 0, stream>>>(H16, Wt1, feat16, al1, ar1, el, er);
    agg_kernel<<<NB, 256, 0, stream>>>(feat16, el, er, rowptr, esrc, H32, b1, H32, H16, nullptr, 1);

    // layer 2 (mean over heads -> d_out)
    gemm_h<<<M_PAD / 128, 512, 0, stream>>>(H16, Wt2, feat16, al2, ar2, el, er);
    agg_kernel<<<NB, 256, 0, stream>>>(feat16, el, er, rowptr, esrc, H32, b2, nullptr, nullptr, out, 0);
}

// Round 5
// 494.298 us; speedup vs baseline: 2.7205x; 1.0477x over previous
//
#include <hip/hip_runtime.h>
#include <math.h>

#define N_NODES 50000
#define N_EDGES 800000
#define F_INPUT 128
#define HEADS 4
#define DHID 64
#define HID 256          // HEADS*DHID
#define M_PAD 50048      // 782*64 = 391*128
#define SCAN_B 49        // ceil(50000/1024)

typedef _Float16 half8 __attribute__((ext_vector_type(8)));
typedef _Float16 half4 __attribute__((ext_vector_type(4)));
typedef float f32x4 __attribute__((ext_vector_type(4)));

// ---------------- CSR build ----------------

__global__ void hist_kernel(const int* __restrict__ dst, int* __restrict__ counts) {
    int e = blockIdx.x * 256 + threadIdx.x;
    if (e < N_EDGES) atomicAdd(&counts[dst[e]], 1);
}

__global__ __launch_bounds__(256) void scan1_kernel(const int* __restrict__ counts,
                                                    int* __restrict__ pre,
                                                    int* __restrict__ bsum) {
    __shared__ int buf[256];
    int tid = threadIdx.x;
    int idx = blockIdx.x * 1024 + tid * 4;
    int v0 = 0, v1 = 0, v2 = 0, v3 = 0;
    if (idx + 3 < N_NODES) {
        int4 v = *(const int4*)&counts[idx];
        v0 = v.x; v1 = v.y; v2 = v.z; v3 = v.w;
    } else {
        if (idx + 0 < N_NODES) v0 = counts[idx + 0];
        if (idx + 1 < N_NODES) v1 = counts[idx + 1];
        if (idx + 2 < N_NODES) v2 = counts[idx + 2];
    }
    int s0 = v0, s1 = s0 + v1, s2 = s1 + v2, s3 = s2 + v3;
    buf[tid] = s3;
    __syncthreads();
    for (int off = 1; off < 256; off <<= 1) {
        int t = (tid >= off) ? buf[tid - off] : 0;
        __syncthreads();
        buf[tid] += t;
        __syncthreads();
    }
    int excl = buf[tid] - s3;
    if (idx + 0 < N_NODES) pre[idx + 0] = excl + s0;
    if (idx + 1 < N_NODES) pre[idx + 1] = excl + s1;
    if (idx + 2 < N_NODES) pre[idx + 2] = excl + s2;
    if (idx + 3 < N_NODES) pre[idx + 3] = excl + s3;
    if (tid == 255) bsum[blockIdx.x] = buf[255];
}

__global__ void scan2_kernel(const int* __restrict__ bsum, int* __restrict__ bpre) {
    int lane = threadIdx.x;
    int v = (lane < SCAN_B) ? bsum[lane] : 0;
    int orig = v;
#pragma unroll
    for (int off = 1; off < 64; off <<= 1) {
        int t = __shfl_up(v, off, 64);
        if (lane >= off) v += t;
    }
    if (lane < SCAN_B) bpre[lane] = v - orig;
}

__global__ __launch_bounds__(256) void scan3_kernel(const int* __restrict__ pre,
                                                    const int* __restrict__ bpre,
                                                    int* __restrict__ row_ptr) {
    int add = bpre[blockIdx.x];
    int idx = blockIdx.x * 1024 + threadIdx.x * 4;
#pragma unroll
    for (int u = 0; u < 4; u++) {
        int i = idx + u;
        if (i < N_NODES) row_ptr[i + 1] = pre[i] + add;
    }
    if (blockIdx.x == 0 && threadIdx.x == 0) row_ptr[0] = 0;
}

__global__ void scatter_kernel(const int* __restrict__ src, const int* __restrict__ dst,
                               const int* __restrict__ row_ptr, int* __restrict__ cursor,
                               int* __restrict__ esrc) {
    int e = blockIdx.x * 256 + threadIdx.x;
    if (e < N_EDGES) {
        int d = dst[e];
        int pos = row_ptr[d] + atomicAdd(&cursor[d], 1);
        esrc[pos] = src[e];
    }
}

// ---------------- conversions ----------------

__global__ void cvt_x_kernel(const float* __restrict__ x, _Float16* __restrict__ x16) {
    int t = blockIdx.x * 256 + threadIdx.x;
    if (t < N_NODES * F_INPUT / 4) {
        f32x4 v = *(const f32x4*)&x[t * 4];
        half4 h = {(_Float16)v.x, (_Float16)v.y, (_Float16)v.z, (_Float16)v.w};
        *(half4*)&x16[(size_t)t * 4] = h;
    }
}

// WtL0 [528 x 128]: rows 0..511 = [W0 | resW0]^T; rows 512..527 filled by wlwr.
// Wt1/Wt2 [272 x 256]: rows 0..255 = W^T; rows 256..271 filled by wlwr.
__global__ void wt_all_kernel(const float* __restrict__ W0, const float* __restrict__ WR,
                              _Float16* __restrict__ WtL0,
                              const float* __restrict__ W1, _Float16* __restrict__ Wt1,
                              const float* __restrict__ W2, _Float16* __restrict__ Wt2) {
    int t = blockIdx.x * 256 + threadIdx.x;
    if (t < 65536) {
        int c = t >> 7;        // 0..511
        int k = t & 127;
        float v = (c < 256) ? W0[k * 256 + c] : WR[k * 256 + (c - 256)];
        WtL0[t] = (_Float16)v;
    } else if (t < 131072) {
        int u = t - 65536;
        int c = u >> 8;
        int k = u & 255;
        Wt1[u] = (_Float16)W1[k * 256 + c];
    } else if (t < 196608) {
        int u = t - 131072;
        int c = u >> 8;
        int k = u & 255;
        Wt2[u] = (_Float16)W2[k * 256 + c];
    }
}

// wl[h,k] = sum_d W[k, h*64+d]*al[h*64+d]; stored as extra Wt rows (8 data + 8 zero).
__global__ void wlwr_kernel(const float* __restrict__ W0, const float* __restrict__ al0,
                            const float* __restrict__ ar0, _Float16* __restrict__ WtL0,
                            const float* __restrict__ W1, const float* __restrict__ al1,
                            const float* __restrict__ ar1, _Float16* __restrict__ Wt1,
                            const float* __restrict__ W2, const float* __restrict__ al2,
                            const float* __restrict__ ar2, _Float16* __restrict__ Wt2) {
    int t = blockIdx.x * 256 + threadIdx.x;
    if (t < 2048) {
        int row8 = t >> 7, k = t & 127;
        float v = 0.f;
        if (row8 < 8) {
            int h = row8 & 3;
            const float* vec = (row8 < 4) ? al0 : ar0;
            float s = 0.f;
            for (int d = 0; d < 64; d++) s += W0[k * 256 + h * 64 + d] * vec[h * 64 + d];
            v = s;
        }
        WtL0[(512 + row8) * 128 + k] = (_Float16)v;
    } else if (t < 6144) {
        int u = t - 2048;
        int row8 = u >> 8, k = u & 255;
        float v = 0.f;
        if (row8 < 8) {
            int h = row8 & 3;
            const float* vec = (row8 < 4) ? al1 : ar1;
            float s = 0.f;
            for (int d = 0; d < 64; d++) s += W1[k * 256 + h * 64 + d] * vec[h * 64 + d];
            v = s;
        }
        Wt1[(256 + row8) * 256 + k] = (_Float16)v;
    } else if (t < 10240) {
        int u = t - 6144;
        int row8 = u >> 8, k = u & 255;
        float v = 0.f;
        if (row8 < 8) {
            int h = row8 & 3;
            const float* vec = (row8 < 4) ? al2 : ar2;
            float s = 0.f;
            for (int d = 0; d < 64; d++) s += W2[k * 256 + h * 64 + d] * vec[h * 64 + d];
            v = s;
        }
        Wt2[(256 + row8) * 256 + k] = (_Float16)v;
    }
}

// ---------------- MFMA GEMMs ----------------

__device__ __forceinline__ void gl2lds16(const void* g, void* l) {
    __builtin_amdgcn_global_load_lds((const __attribute__((address_space(1))) void*)g,
                                     (__attribute__((address_space(3))) void*)l, 16, 0, 0);
}

// layer 0: C[M x 528] = x16[M x 128] * WtL0^T. 64 rows x {512 cols + elr tile} per block.
// waves 0..3: feat cols (w*64..), wave 3 also the elr tile; waves 4..7: res cols (fp16).
__global__ __launch_bounds__(512) void gemm_l0(const _Float16* __restrict__ A16,
                                               const _Float16* __restrict__ WtL0,
                                               _Float16* __restrict__ feat16,
                                               _Float16* __restrict__ res16,
                                               float* __restrict__ el, float* __restrict__ er) {
    __shared__ __align__(16) _Float16 As[4 * 512];
    __shared__ __align__(16) _Float16 Ws[33 * 512];
    int tid = threadIdx.x;
    int w = tid >> 6;
    int lane = tid & 63;
    int lrow = lane & 15;
    int lk = lane >> 4;
    int row0 = blockIdx.x * 64;

    f32x4 acc[4][4] = {};
    f32x4 acc5[4] = {};

    for (int k0 = 0; k0 < F_INPUT; k0 += 32) {
        if (w < 4)
            gl2lds16(A16 + (size_t)(row0 + w * 16 + lrow) * F_INPUT + k0 + lk * 8, &As[w * 512]);
#pragma unroll
        for (int i = 0; i < 4; i++) {
            int tt = i * 8 + w;
            gl2lds16(WtL0 + (size_t)(tt * 16 + lrow) * F_INPUT + k0 + lk * 8, &Ws[tt * 512]);
        }
        if (w == 7)
            gl2lds16(WtL0 + (size_t)(512 + lrow) * F_INPUT + k0 + lk * 8, &Ws[32 * 512]);
        __syncthreads();
        half8 a[4], b[4], b5;
#pragma unroll
        for (int m = 0; m < 4; m++) a[m] = *(const half8*)&As[m * 512 + lane * 8];
#pragma unroll
        for (int j = 0; j < 4; j++) b[j] = *(const half8*)&Ws[(w * 4 + j) * 512 + lane * 8];
        if (w == 3) b5 = *(const half8*)&Ws[32 * 512 + lane * 8];
#pragma unroll
        for (int m = 0; m < 4; m++)
#pragma unroll
            for (int j = 0; j < 4; j++)
                acc[m][j] = __builtin_amdgcn_mfma_f32_16x16x32_f16(a[m], b[j], acc[m][j], 0, 0, 0);
        if (w == 3) {
#pragma unroll
            for (int m = 0; m < 4; m++)
                acc5[m] = __builtin_amdgcn_mfma_f32_16x16x32_f16(a[m], b5, acc5[m], 0, 0, 0);
        }
        __syncthreads();
    }

    if (w < 4) {
#pragma unroll
        for (int m = 0; m < 4; m++) {
#pragma unroll
            for (int r = 0; r < 4; r++) {
                int row = row0 + m * 16 + lk * 4 + r;
                if (row < N_NODES) {
#pragma unroll
                    for (int j = 0; j < 4; j++)
                        feat16[(size_t)row * HID + w * 64 + j * 16 + lrow] = (_Float16)acc[m][j][r];
                }
            }
        }
        if (w == 3 && lrow < 8) {
#pragma unroll
            for (int m = 0; m < 4; m++) {
#pragma unroll
                for (int r = 0; r < 4; r++) {
                    int row = row0 + m * 16 + lk * 4 + r;
                    if (row < N_NODES) {
                        float v = acc5[m][r];
                        if (lrow < 4) el[row * 4 + lrow] = v;
                        else          er[row * 4 + (lrow - 4)] = v;
                    }
                }
            }
        }
    } else {
        int wc = w - 4;
#pragma unroll
        for (int m = 0; m < 4; m++) {
#pragma unroll
            for (int r = 0; r < 4; r++) {
                int row = row0 + m * 16 + lk * 4 + r;
                if (row < N_NODES) {
#pragma unroll
                    for (int j = 0; j < 4; j++)
                        res16[(size_t)row * HID + wc * 64 + j * 16 + lrow] = (_Float16)acc[m][j][r];
                }
            }
        }
    }
}

// layers 1/2: C[M x 256(+elr)] = A16[M x 256] * Wt^T. 128 rows x 256 cols per block,
// 8 waves in 2(row)x4(col); wcol==3 waves also compute the elr tile (Wt rows 256..271).
__global__ __launch_bounds__(512) void gemm_h(const _Float16* __restrict__ A16,
                                              const _Float16* __restrict__ Wt,
                                              _Float16* __restrict__ feat16,
                                              float* __restrict__ el, float* __restrict__ er) {
    __shared__ __align__(16) _Float16 As[8 * 512];
    __shared__ __align__(16) _Float16 Ws[17 * 512];
    int tid = threadIdx.x;
    int w = tid >> 6;
    int lane = tid & 63;
    int lrow = lane & 15;
    int lk = lane >> 4;
    int wrow = w >> 2;
    int wcol = w & 3;
    int row0 = blockIdx.x * 128;

    f32x4 acc[4][4] = {};
    f32x4 acc5[4] = {};

    for (int k0 = 0; k0 < HID; k0 += 32) {
        gl2lds16(A16 + (size_t)(row0 + w * 16 + lrow) * HID + k0 + lk * 8, &As[w * 512]);
        gl2lds16(Wt + (size_t)(w * 16 + lrow) * HID + k0 + lk * 8, &Ws[w * 512]);
        gl2lds16(Wt + (size_t)((w + 8) * 16 + lrow) * HID + k0 + lk * 8, &Ws[(w + 8) * 512]);
        if (w == 0)
            gl2lds16(Wt + (size_t)(256 + lrow) * HID + k0 + lk * 8, &Ws[16 * 512]);
        __syncthreads();
        half8 a[4], b[4], b5;
#pragma unroll
        for (int m = 0; m < 4; m++) a[m] = *(const half8*)&As[(wrow * 4 + m) * 512 + lane * 8];
#pragma unroll
        for (int j = 0; j < 4; j++) b[j] = *(const half8*)&Ws[(wcol * 4 + j) * 512 + lane * 8];
        if (wcol == 3) b5 = *(const half8*)&Ws[16 * 512 + lane * 8];
#pragma unroll
        for (int m = 0; m < 4; m++)
#pragma unroll
            for (int j = 0; j < 4; j++)
                acc[m][j] = __builtin_amdgcn_mfma_f32_16x16x32_f16(a[m], b[j], acc[m][j], 0, 0, 0);
        if (wcol == 3) {
#pragma unroll
            for (int m = 0; m < 4; m++)
                acc5[m] = __builtin_amdgcn_mfma_f32_16x16x32_f16(a[m], b5, acc5[m], 0, 0, 0);
        }
        __syncthreads();
    }

#pragma unroll
    for (int m = 0; m < 4; m++) {
#pragma unroll
        for (int r = 0; r < 4; r++) {
            int row = row0 + wrow * 64 + m * 16 + lk * 4 + r;
            if (row < N_NODES) {
#pragma unroll
                for (int j = 0; j < 4; j++)
                    feat16[(size_t)row * HID + wcol * 64 + j * 16 + lrow] = (_Float16)acc[m][j][r];
            }
        }
    }
    if (wcol == 3 && lrow < 8) {
#pragma unroll
        for (int m = 0; m < 4; m++) {
#pragma unroll
            for (int r = 0; r < 4; r++) {
                int row = row0 + wrow * 64 + m * 16 + lk * 4 + r;
                if (row < N_NODES) {
                    float v = acc5[m][r];
                    if (lrow < 4) el[row * 4 + lrow] = v;
                    else          er[row * 4 + (lrow - 4)] = v;
                }
            }
        }
    }
}

// ---------------- softmax + aggregation + epilogue ----------------
// one wave per node; lane covers dims lane*4..+3, head = lane>>4. fp16 residual.

__global__ __launch_bounds__(256) void agg_kernel(const _Float16* __restrict__ feat16,
                                                  const float* __restrict__ el,
                                                  const float* __restrict__ er,
                                                  const int* __restrict__ row_ptr,
                                                  const int* __restrict__ esrc,
                                                  const _Float16* __restrict__ res16,
                                                  const float* __restrict__ bias,
                                                  _Float16* __restrict__ out16,
                                                  float* __restrict__ outmean,
                                                  int do_relu) {
    __shared__ float lds[4][64 * 5];
    int wv = threadIdx.x >> 6;
    int lane = threadIdx.x & 63;
    int n = blockIdx.x * 4 + wv;
    int head = lane >> 4;
    int start = row_ptr[n];
    int deg = row_ptr[n + 1] - start;
    f32x4 ern = *(const f32x4*)&er[n * 4];
    float* L = lds[wv];

    f32x4 acc = {0.f, 0.f, 0.f, 0.f};
    float smh = 0.f;

    if (deg <= 64) {
        int s = 0;
        f32x4 x = {-1e30f, -1e30f, -1e30f, -1e30f};
        if (lane < deg) {
            s = esrc[start + lane];
            f32x4 v = *(const f32x4*)&el[s * 4];
            v = v + ern;
            x.x = v.x > 0.f ? v.x : 0.2f * v.x;
            x.y = v.y > 0.f ? v.y : 0.2f * v.y;
            x.z = v.z > 0.f ? v.z : 0.2f * v.z;
            x.w = v.w > 0.f ? v.w : 0.2f * v.w;
        }
        f32x4 cm = x;
#pragma unroll
        for (int off = 1; off < 64; off <<= 1) {
            cm.x = fmaxf(cm.x, __shfl_xor(cm.x, off, 64));
            cm.y = fmaxf(cm.y, __shfl_xor(cm.y, off, 64));
            cm.z = fmaxf(cm.z, __shfl_xor(cm.z, off, 64));
            cm.w = fmaxf(cm.w, __shfl_xor(cm.w, off, 64));
        }
        f32x4 ex4;
        ex4.x = __expf(x.x - cm.x);
        ex4.y = __expf(x.y - cm.y);
        ex4.z = __expf(x.z - cm.z);
        ex4.w = __expf(x.w - cm.w);
        L[lane * 5 + 0] = ex4.x;
        L[lane * 5 + 1] = ex4.y;
        L[lane * 5 + 2] = ex4.z;
        L[lane * 5 + 3] = ex4.w;
        L[lane * 5 + 4] = __int_as_float(s);
        f32x4 cs = ex4;
#pragma unroll
        for (int off = 1; off < 64; off <<= 1) {
            cs.x += __shfl_xor(cs.x, off, 64);
            cs.y += __shfl_xor(cs.y, off, 64);
            cs.z += __shfl_xor(cs.z, off, 64);
            cs.w += __shfl_xor(cs.w, off, 64);
        }
        smh = (head == 0) ? cs.x : (head == 1) ? cs.y : (head == 2) ? cs.z : cs.w;

        int j = 0;
        for (; j + 4 <= deg; j += 4) {
            float exv[4]; int ssv[4];
#pragma unroll
            for (int u = 0; u < 4; u++) {
                exv[u] = L[(j + u) * 5 + head];
                ssv[u] = __float_as_int(L[(j + u) * 5 + 4]);
            }
            half4 f[4];
#pragma unroll
            for (int u = 0; u < 4; u++)
                f[u] = *(const half4*)&feat16[(size_t)ssv[u] * HID + lane * 4];
#pragma unroll
            for (int u = 0; u < 4; u++) {
                acc.x += exv[u] * (float)f[u].x;
                acc.y += exv[u] * (float)f[u].y;
                acc.z += exv[u] * (float)f[u].z;
                acc.w += exv[u] * (float)f[u].w;
            }
        }
        for (; j < deg; j++) {
            float ex = L[j * 5 + head];
            int ss = __float_as_int(L[j * 5 + 4]);
            half4 f = *(const half4*)&feat16[(size_t)ss * HID + lane * 4];
            acc.x += ex * (float)f.x;
            acc.y += ex * (float)f.y;
            acc.z += ex * (float)f.z;
            acc.w += ex * (float)f.w;
        }
    } else {
        f32x4 mx = {-1e30f, -1e30f, -1e30f, -1e30f};
        for (int base = 0; base < deg; base += 64) {
            int e = base + lane;
            int s = 0;
            f32x4 x = {-1e30f, -1e30f, -1e30f, -1e30f};
            if (e < deg) {
                s = esrc[start + e];
                f32x4 v = *(const f32x4*)&el[s * 4];
                v = v + ern;
                x.x = v.x > 0.f ? v.x : 0.2f * v.x;
                x.y = v.y > 0.f ? v.y : 0.2f * v.y;
                x.z = v.z > 0.f ? v.z : 0.2f * v.z;
                x.w = v.w > 0.f ? v.w : 0.2f * v.w;
            }
            f32x4 cm = x;
#pragma unroll
            for (int off = 1; off < 64; off <<= 1) {
                cm.x = fmaxf(cm.x, __shfl_xor(cm.x, off, 64));
                cm.y = fmaxf(cm.y, __shfl_xor(cm.y, off, 64));
                cm.z = fmaxf(cm.z, __shfl_xor(cm.z, off, 64));
                cm.w = fmaxf(cm.w, __shfl_xor(cm.w, off, 64));
            }
            f32x4 nmx;
            nmx.x = fmaxf(mx.x, cm.x);
            nmx.y = fmaxf(mx.y, cm.y);
            nmx.z = fmaxf(mx.z, cm.z);
            nmx.w = fmaxf(mx.w, cm.w);
            float mxh  = (head == 0) ? mx.x  : (head == 1) ? mx.y  : (head == 2) ? mx.z  : mx.w;
            float nmxh = (head == 0) ? nmx.x : (head == 1) ? nmx.y : (head == 2) ? nmx.z : nmx.w;
            float sc = __expf(mxh - nmxh);
            smh *= sc;
            acc = acc * sc;
            f32x4 ex4;
            ex4.x = __expf(x.x - nmx.x);
            ex4.y = __expf(x.y - nmx.y);
            ex4.z = __expf(x.z - nmx.z);
            ex4.w = __expf(x.w - nmx.w);
            L[lane * 5 + 0] = ex4.x;
            L[lane * 5 + 1] = ex4.y;
            L[lane * 5 + 2] = ex4.z;
            L[lane * 5 + 3] = ex4.w;
            L[lane * 5 + 4] = __int_as_float(s);
            f32x4 cs = ex4;
#pragma unroll
            for (int off = 1; off < 64; off <<= 1) {
                cs.x += __shfl_xor(cs.x, off, 64);
                cs.y += __shfl_xor(cs.y, off, 64);
                cs.z += __shfl_xor(cs.z, off, 64);
                cs.w += __shfl_xor(cs.w, off, 64);
            }
            smh += (head == 0) ? cs.x : (head == 1) ? cs.y : (head == 2) ? cs.z : cs.w;

            int cnt = min(64, deg - base);
            int j = 0;
            for (; j + 4 <= cnt; j += 4) {
                float exv[4]; int ssv[4];
#pragma unroll
                for (int u = 0; u < 4; u++) {
                    exv[u] = L[(j + u) * 5 + head];
                    ssv[u] = __float_as_int(L[(j + u) * 5 + 4]);
                }
                half4 f[4];
#pragma unroll
                for (int u = 0; u < 4; u++)
                    f[u] = *(const half4*)&feat16[(size_t)ssv[u] * HID + lane * 4];
#pragma unroll
                for (int u = 0; u < 4; u++) {
                    acc.x += exv[u] * (float)f[u].x;
                    acc.y += exv[u] * (float)f[u].y;
                    acc.z += exv[u] * (float)f[u].z;
                    acc.w += exv[u] * (float)f[u].w;
                }
            }
            for (; j < cnt; j++) {
                float ex = L[j * 5 + head];
                int ss = __float_as_int(L[j * 5 + 4]);
                half4 f = *(const half4*)&feat16[(size_t)ss * HID + lane * 4];
                acc.x += ex * (float)f.x;
                acc.y += ex * (float)f.y;
                acc.z += ex * (float)f.z;
                acc.w += ex * (float)f.w;
            }
            mx = nmx;
        }
    }

    float inv = 1.f / fmaxf(smh, 1e-16f);
    f32x4 o = acc * inv;
    half4 rv = *(const half4*)&res16[(size_t)n * HID + lane * 4];
    f32x4 bv = *(const f32x4*)&bias[lane * 4];
    o.x += (float)rv.x + bv.x;
    o.y += (float)rv.y + bv.y;
    o.z += (float)rv.z + bv.z;
    o.w += (float)rv.w + bv.w;
    if (do_relu) {
        o.x = fmaxf(o.x, 0.f);
        o.y = fmaxf(o.y, 0.f);
        o.z = fmaxf(o.z, 0.f);
        o.w = fmaxf(o.w, 0.f);
    }
    if (outmean) {
        o.x += __shfl_xor(o.x, 16, 64); o.x += __shfl_xor(o.x, 32, 64);
        o.y += __shfl_xor(o.y, 16, 64); o.y += __shfl_xor(o.y, 32, 64);
        o.z += __shfl_xor(o.z, 16, 64); o.z += __shfl_xor(o.z, 32, 64);
        o.w += __shfl_xor(o.w, 16, 64); o.w += __shfl_xor(o.w, 32, 64);
        if (head == 0) {
            f32x4 mo = o * 0.25f;
            *(f32x4*)&outmean[(size_t)n * DHID + (lane & 15) * 4] = mo;
        }
    } else {
        half4 h = {(_Float16)o.x, (_Float16)o.y, (_Float16)o.z, (_Float16)o.w};
        *(half4*)&out16[(size_t)n * HID + lane * 4] = h;
    }
}

// ---------------- launch ----------------

extern "C" void kernel_launch(void* const* d_in, const int* in_sizes, int n_in,
                              void* d_out, int out_size, void* d_ws, size_t ws_size,
                              hipStream_t stream) {
    const float* x     = (const float*)d_in[0];
    const int*   ei    = (const int*)d_in[1];
    const float* W0    = (const float*)d_in[2];
    const float* W1    = (const float*)d_in[3];
    const float* W2    = (const float*)d_in[4];
    const float* al0   = (const float*)d_in[5];
    const float* al1   = (const float*)d_in[6];
    const float* al2   = (const float*)d_in[7];
    const float* ar0   = (const float*)d_in[8];
    const float* ar1   = (const float*)d_in[9];
    const float* ar2   = (const float*)d_in[10];
    const float* b0    = (const float*)d_in[11];
    const float* b1    = (const float*)d_in[12];
    const float* b2    = (const float*)d_in[13];
    const float* resW0 = (const float*)d_in[14];
    float* out = (float*)d_out;

    const int* srcp = ei;
    const int* dstp = ei + N_EDGES;

    char* p = (char*)d_ws;
    auto alloc = [&](size_t bytes) -> char* {
        char* r = p;
        p += (bytes + 255) & ~(size_t)255;
        return r;
    };
    _Float16*  h16    = (_Float16*)alloc((size_t)M_PAD * HID * 2);     // agg out / GEMM in / res
    _Float16*  feat16 = (_Float16*)alloc((size_t)M_PAD * HID * 2);     // GEMM out
    _Float16*  res0   = (_Float16*)alloc((size_t)N_NODES * HID * 2);   // layer-0 residual
    _Float16*  x16    = (_Float16*)alloc((size_t)M_PAD * F_INPUT * 2);
    float*     el     = (float*)alloc((size_t)N_NODES * HEADS * 4);
    float*     er     = (float*)alloc((size_t)N_NODES * HEADS * 4);
    _Float16*  WtL0   = (_Float16*)alloc((size_t)528 * F_INPUT * 2);
    _Float16*  Wt1    = (_Float16*)alloc((size_t)272 * HID * 2);
    _Float16*  Wt2    = (_Float16*)alloc((size_t)272 * HID * 2);
    int*       counts = (int*)alloc((size_t)2 * N_NODES * 4);   // counts + cursor
    int*       cursor = counts + N_NODES;
    int*       rowptr = (int*)alloc((size_t)(N_NODES + 1) * 4);
    int*       esrc   = (int*)alloc((size_t)N_EDGES * 4);
    int*       pre    = (int*)alloc((size_t)N_NODES * 4);
    int*       bsum   = (int*)alloc((size_t)SCAN_B * 4);
    int*       bpre   = (int*)alloc((size_t)SCAN_B * 4);

    const int EB = (N_EDGES + 255) / 256;
    const int NB = N_NODES / 4;

    // CSR by dst
    hipMemsetAsync(counts, 0, (size_t)2 * N_NODES * 4, stream);
    hist_kernel<<<EB, 256, 0, stream>>>(dstp, counts);
    scan1_kernel<<<SCAN_B, 256, 0, stream>>>(counts, pre, bsum);
    scan2_kernel<<<1, 64, 0, stream>>>(bsum, bpre);
    scan3_kernel<<<SCAN_B, 256, 0, stream>>>(pre, bpre, rowptr);
    scatter_kernel<<<EB, 256, 0, stream>>>(srcp, dstp, rowptr, cursor, esrc);

    // conversions
    cvt_x_kernel<<<(N_NODES * F_INPUT / 4 + 255) / 256, 256, 0, stream>>>(x, x16);
    wt_all_kernel<<<768, 256, 0, stream>>>(W0, resW0, WtL0, W1, Wt1, W2, Wt2);
    wlwr_kernel<<<40, 256, 0, stream>>>(W0, al0, ar0, WtL0, W1, al1, ar1, Wt1, W2, al2, ar2, Wt2);

    // layer 0
    gemm_l0<<<M_PAD / 64, 512, 0, stream>>>(x16, WtL0, feat16, res0, el, er);
    agg_kernel<<<NB, 256, 0, stream>>>(feat16, el, er, rowptr, esrc, res0, b0, h16, nullptr, 1);

    // layer 1 (in-place: res = h16, out = h16)
    gemm_h<<<M_PAD / 128, 512, 0, stream>>>(h16, Wt1, feat16, el, er);
    agg_kernel<<<NB, 256, 0, stream>>>(feat16, el, er, rowptr, esrc, h16, b1, h16, nullptr, 1);

    // layer 2 (mean over heads -> d_out)
    gemm_h<<<M_PAD / 128, 512, 0, stream>>>(h16, Wt2, feat16, el, er);
    agg_kernel<<<NB, 256, 0, stream>>>(feat16, el, er, rowptr, esrc, h16, b2, nullptr, out, 0);
}